// Round 2
// baseline (5074.887 us; speedup 1.0000x reference)
//
#include <hip/hip_runtime.h>
#include <hip/hip_bf16.h>

#define HDIM 256
#define NEG_SLOPE 0.2f

// ---------------------------------------------------------------- utilities
__global__ void fillf_kernel(float* __restrict__ p, float v, int n) {
  int i = blockIdx.x * blockDim.x + threadIdx.x;
  if (i < n) p[i] = v;
}

// ---------------------------------------------------------------- GEMM
// C[M,N] = act(A[M,K] @ B[K,N] + bias(opt)), all fp32.
// 64x64 tile, BK=16, 256 threads, 4x4 micro-tile per thread. ACT: 0=none,1=relu
#define BM 64
#define BN 64
#define BK 16

template <int ACT>
__global__ __launch_bounds__(256) void gemm_ab(
    const float* __restrict__ A, const float* __restrict__ B,
    const float* __restrict__ bias, float* __restrict__ C,
    int M, int N, int K) {
  __shared__ float As[BK][BM + 1];
  __shared__ float Bs[BK][BN + 1];
  const int tid = threadIdx.x;
  const int tx = tid & 15, ty = tid >> 4;
  const int m0 = blockIdx.y * BM;
  const int n0 = blockIdx.x * BN;
  float acc[4][4] = {};

  for (int k0 = 0; k0 < K; k0 += BK) {
    // A tile: 64 rows x 16 cols (K multiple of 16, rows 16B-aligned)
    {
      int r = tid >> 2;
      int c = (tid & 3) * 4;
      int gm = m0 + r;
      float4 v = make_float4(0.f, 0.f, 0.f, 0.f);
      if (gm < M) v = *(const float4*)(A + (size_t)gm * K + k0 + c);
      As[c + 0][r] = v.x; As[c + 1][r] = v.y;
      As[c + 2][r] = v.z; As[c + 3][r] = v.w;
    }
    // B tile: 16 rows x 64 cols (scalar loads; handles any N incl. N=2)
    {
      int r = tid >> 4;           // 0..15
      int c = (tid & 15) * 4;     // 0..60
      const float* bp = B + (size_t)(k0 + r) * N + n0 + c;
#pragma unroll
      for (int u = 0; u < 4; ++u) {
        int gn = n0 + c + u;
        Bs[r][c + u] = (gn < N) ? bp[u] : 0.f;
      }
    }
    __syncthreads();
#pragma unroll
    for (int kk = 0; kk < BK; ++kk) {
      float av[4], bv[4];
#pragma unroll
      for (int i = 0; i < 4; ++i) av[i] = As[kk][ty * 4 + i];
#pragma unroll
      for (int j = 0; j < 4; ++j) bv[j] = Bs[kk][tx * 4 + j];
#pragma unroll
      for (int i = 0; i < 4; ++i)
#pragma unroll
        for (int j = 0; j < 4; ++j) acc[i][j] += av[i] * bv[j];
    }
    __syncthreads();
  }

#pragma unroll
  for (int i = 0; i < 4; ++i) {
    int gm = m0 + ty * 4 + i;
    if (gm >= M) continue;
#pragma unroll
    for (int j = 0; j < 4; ++j) {
      int gn = n0 + tx * 4 + j;
      if (gn >= N) continue;
      float v = acc[i][j];
      if (bias) v += bias[gn];
      if (ACT == 1) v = fmaxf(v, 0.f);
      C[(size_t)gm * N + gn] = v;
    }
  }
}

// First MLP layer with fused gather:
// A[i, 0:256]=xdn[d1[i]], A[i,256:512]=xdn[d2[i]], A[i,512:768]=xcn[cc[i]]
// C = relu(A @ B + bias). K=768 fixed. Batch rows offset by row0.
__global__ __launch_bounds__(256) void gemm_hid(
    const float* __restrict__ xdn, const float* __restrict__ xcn,
    const int* __restrict__ d1, const int* __restrict__ d2, const int* __restrict__ cc,
    const float* __restrict__ B, const float* __restrict__ bias,
    float* __restrict__ C, int row0, int M, int N) {
  const int K = 768;
  __shared__ float As[BK][BM + 1];
  __shared__ float Bs[BK][BN + 1];
  const int tid = threadIdx.x;
  const int tx = tid & 15, ty = tid >> 4;
  const int m0 = blockIdx.y * BM;
  const int n0 = blockIdx.x * BN;
  float acc[4][4] = {};

  for (int k0 = 0; k0 < K; k0 += BK) {
    {
      int r = tid >> 2;
      int c = (tid & 3) * 4;
      int gm = m0 + r;
      float4 v = make_float4(0.f, 0.f, 0.f, 0.f);
      if (gm < M) {
        int bi = row0 + gm;
        int seg = k0 >> 8;                 // BK=16 tile never crosses a 256 boundary
        const float* tab;
        int idx;
        if (seg == 0)      { tab = xdn; idx = d1[bi]; }
        else if (seg == 1) { tab = xdn; idx = d2[bi]; }
        else               { tab = xcn; idx = cc[bi]; }
        v = *(const float4*)(tab + (size_t)idx * HDIM + (k0 & 255) + c);
      }
      As[c + 0][r] = v.x; As[c + 1][r] = v.y;
      As[c + 2][r] = v.z; As[c + 3][r] = v.w;
    }
    {
      int r = tid >> 4;
      int c = (tid & 15) * 4;
      const float* bp = B + (size_t)(k0 + r) * N + n0 + c;
#pragma unroll
      for (int u = 0; u < 4; ++u) {
        int gn = n0 + c + u;
        Bs[r][c + u] = (gn < N) ? bp[u] : 0.f;
      }
    }
    __syncthreads();
#pragma unroll
    for (int kk = 0; kk < BK; ++kk) {
      float av[4], bv[4];
#pragma unroll
      for (int i = 0; i < 4; ++i) av[i] = As[kk][ty * 4 + i];
#pragma unroll
      for (int j = 0; j < 4; ++j) bv[j] = Bs[kk][tx * 4 + j];
#pragma unroll
      for (int i = 0; i < 4; ++i)
#pragma unroll
        for (int j = 0; j < 4; ++j) acc[i][j] += av[i] * bv[j];
    }
    __syncthreads();
  }

#pragma unroll
  for (int i = 0; i < 4; ++i) {
    int gm = m0 + ty * 4 + i;
    if (gm >= M) continue;
#pragma unroll
    for (int j = 0; j < 4; ++j) {
      int gn = n0 + tx * 4 + j;
      if (gn >= N) continue;
      float v = acc[i][j] + bias[gn];
      C[(size_t)gm * N + gn] = fmaxf(v, 0.f);
    }
  }
}

// ---------------------------------------------------------------- row dot: out[r] = H[r,:] . a
__global__ __launch_bounds__(64) void rowdot_kernel(
    const float* __restrict__ H, const float* __restrict__ a,
    float* __restrict__ out, int n) {
  int row = blockIdx.x;
  if (row >= n) return;
  int lane = threadIdx.x;
  const float* h = H + (size_t)row * HDIM;
  float s = 0.f;
#pragma unroll
  for (int u = 0; u < 4; ++u) {
    int c = lane + u * 64;
    s += h[c] * a[c];
  }
#pragma unroll
  for (int off = 32; off; off >>= 1) s += __shfl_down(s, off);
  if (lane == 0) out[row] = s;
}

// ---------------------------------------------------------------- edge passes
__device__ inline void atomicMaxF(float* addr, float val) {
  if (val >= 0.f)
    atomicMax((int*)addr, __float_as_int(val));
  else
    atomicMin((unsigned int*)addr, __float_as_uint(val));
}

// pass1: e = leaky_relu(als[src]+ald[dst]); store e; m[dst] = max(m[dst], e)
__global__ void edge_pass1_kernel(const int* __restrict__ src, const int* __restrict__ dst,
                                  int E, int nloops,
                                  const float* __restrict__ als, const float* __restrict__ ald,
                                  float* __restrict__ ebuf, float* __restrict__ m) {
  int i = blockIdx.x * blockDim.x + threadIdx.x;
  int tot = E + nloops;
  if (i >= tot) return;
  int s_, d_;
  if (i < E) { s_ = src[i]; d_ = dst[i]; }
  else       { s_ = d_ = i - E; }
  float v = als[s_] + ald[d_];
  v = (v > 0.f) ? v : NEG_SLOPE * v;
  ebuf[i] = v;
  atomicMaxF(&m[d_], v);
}

// pass2: ex = exp(e - m[dst]); store ex; denom[dst] += ex
__global__ void edge_pass2_kernel(const int* __restrict__ dst, int E, int nloops,
                                  const float* __restrict__ m,
                                  float* __restrict__ ebuf, float* __restrict__ denom) {
  int i = blockIdx.x * blockDim.x + threadIdx.x;
  int tot = E + nloops;
  if (i >= tot) return;
  int d_ = (i < E) ? dst[i] : (i - E);
  float ex = __expf(ebuf[i] - m[d_]);
  ebuf[i] = ex;
  atomicAdd(&denom[d_], ex);
}

// pass3: out[dst,:] += (ex/denom[dst]) * H[src,:]   (one wave per edge)
__global__ __launch_bounds__(256) void edge_aggregate_kernel(
    const int* __restrict__ src, const int* __restrict__ dst, int E, int nloops,
    const float* __restrict__ ebuf, const float* __restrict__ denom,
    const float* __restrict__ H, float* __restrict__ out) {
  int e = blockIdx.x * 4 + (threadIdx.x >> 6);
  int lane = threadIdx.x & 63;
  int tot = E + nloops;
  if (e >= tot) return;
  int s_, d_;
  if (e < E) { s_ = src[e]; d_ = dst[e]; }
  else       { s_ = d_ = e - E; }
  float coef = ebuf[e] / (denom[d_] + 1e-16f);
  const float* h = H + (size_t)s_ * HDIM;
  float* o = out + (size_t)d_ * HDIM;
#pragma unroll
  for (int u = 0; u < 4; ++u) {
    int c = lane + u * 64;
    atomicAdd(&o[c], coef * h[c]);
  }
}

// ---------------------------------------------------------------- finalize
// l2norm(acc + bias) per row (bias optional)
__global__ __launch_bounds__(64) void l2norm_bias_kernel(
    const float* __restrict__ acc, const float* __restrict__ bias,
    float* __restrict__ xout, int n) {
  int row = blockIdx.x;
  if (row >= n) return;
  int lane = threadIdx.x;
  float v[4];
  float ss = 0.f;
#pragma unroll
  for (int u = 0; u < 4; ++u) {
    int c = lane + u * 64;
    float t = acc[(size_t)row * HDIM + c];
    if (bias) t += bias[c];
    v[u] = t;
    ss += t * t;
  }
#pragma unroll
  for (int off = 32; off; off >>= 1) ss += __shfl_xor(ss, off);
  float sc = 1.0f / fmaxf(sqrtf(ss), 1e-12f);
#pragma unroll
  for (int u = 0; u < 4; ++u) {
    int c = lane + u * 64;
    xout[(size_t)row * HDIM + c] = v[u] * sc;
  }
}

__global__ void relu_bias_kernel(const float* __restrict__ acc, const float* __restrict__ bias,
                                 float* __restrict__ xout, int total) {
  int i = blockIdx.x * blockDim.x + threadIdx.x;
  if (i >= total) return;
  int c = i & (HDIM - 1);
  xout[i] = fmaxf(acc[i] + bias[c], 0.f);
}

// ---------------------------------------------------------------- host side
static inline int cdiv(int a, int b) { return (a + b - 1) / b; }

struct GatBufs {
  float *Hsrc, *Hdst, *als, *ald, *m, *den, *ebuf, *out;
};

static void run_gat(hipStream_t stream,
                    const float* Xsrc, int Ns, const float* Xdst, int Nd,
                    const float* W, const float* asrc, const float* adst, const float* bias,
                    const int* esrc, const int* edst, int E, int nloops,
                    const GatBufs& b, float* xout, int act /*0=l2norm,1=relu*/) {
  // h = x @ W
  dim3 g1(cdiv(HDIM, BN), cdiv(Ns, BM));
  gemm_ab<0><<<g1, 256, 0, stream>>>(Xsrc, W, nullptr, b.Hsrc, Ns, HDIM, HDIM);
  const float* Hd = b.Hsrc;
  if (Xdst != Xsrc) {
    dim3 g2(cdiv(HDIM, BN), cdiv(Nd, BM));
    gemm_ab<0><<<g2, 256, 0, stream>>>(Xdst, W, nullptr, b.Hdst, Nd, HDIM, HDIM);
    Hd = b.Hdst;
  }
  // attention logits per node
  rowdot_kernel<<<Ns, 64, 0, stream>>>(b.Hsrc, asrc, b.als, Ns);
  rowdot_kernel<<<Nd, 64, 0, stream>>>(Hd, adst, b.ald, Nd);
  // init reductions
  fillf_kernel<<<cdiv(Nd, 256), 256, 0, stream>>>(b.m, -1e30f, Nd);
  fillf_kernel<<<cdiv(Nd, 256), 256, 0, stream>>>(b.den, 0.f, Nd);
  fillf_kernel<<<cdiv(Nd * HDIM, 256), 256, 0, stream>>>(b.out, 0.f, Nd * HDIM);
  int tot = E + nloops;
  edge_pass1_kernel<<<cdiv(tot, 256), 256, 0, stream>>>(esrc, edst, E, nloops, b.als, b.ald, b.ebuf, b.m);
  edge_pass2_kernel<<<cdiv(tot, 256), 256, 0, stream>>>(edst, E, nloops, b.m, b.ebuf, b.den);
  edge_aggregate_kernel<<<cdiv(tot, 4), 256, 0, stream>>>(esrc, edst, E, nloops, b.ebuf, b.den, b.Hsrc, b.out);
  if (act == 0)
    l2norm_bias_kernel<<<Nd, 64, 0, stream>>>(b.out, bias, xout, Nd);
  else
    relu_bias_kernel<<<cdiv(Nd * HDIM, 256), 256, 0, stream>>>(b.out, bias, xout, Nd * HDIM);
}

extern "C" void kernel_launch(void* const* d_in, const int* in_sizes, int n_in,
                              void* d_out, int out_size, void* d_ws, size_t ws_size,
                              hipStream_t stream) {
  // All float tensors in the reference are float32.
  const float* drug_emb = (const float*)d_in[0];
  const float* prot_emb = (const float*)d_in[1];
  const float* cell_emb = (const float*)d_in[2];
  const float* W_pp = (const float*)d_in[3];
  const float* as_pp = (const float*)d_in[4];
  const float* ad_pp = (const float*)d_in[5];
  const float* b_pp = (const float*)d_in[6];
  const float* W_dp = (const float*)d_in[7];
  const float* as_dp = (const float*)d_in[8];
  const float* ad_dp = (const float*)d_in[9];
  const float* b_dp = (const float*)d_in[10];
  const float* W_cp = (const float*)d_in[11];
  const float* as_cp = (const float*)d_in[12];
  const float* ad_cp = (const float*)d_in[13];
  const float* b_cp = (const float*)d_in[14];
  const float* W1 = (const float*)d_in[15];
  const float* b1 = (const float*)d_in[16];
  const float* W2 = (const float*)d_in[17];
  const float* b2 = (const float*)d_in[18];
  const float* W3 = (const float*)d_in[19];
  const float* b3 = (const float*)d_in[20];
  const int* edge_pp = (const int*)d_in[21];
  const int* edge_dp = (const int*)d_in[22];
  const int* edge_cp = (const int*)d_in[23];
  const int* drug1 = (const int*)d_in[24];
  const int* drug2 = (const int*)d_in[25];
  const int* cellb = (const int*)d_in[26];

  const int ND = in_sizes[0] / HDIM;   // 2000
  const int NP = in_sizes[1] / HDIM;   // 19000
  const int NC = in_sizes[2] / HDIM;   // 100
  const int L = in_sizes[3] / (HDIM * HDIM);  // 2
  const int E_pp = in_sizes[21] / 2;   // 400000
  const int E_dp = in_sizes[22] / 2;   // 60000
  const int E_cp = in_sizes[23] / 2;   // 300000
  const int B = in_sizes[24];          // 8192

  const int* src_pp = edge_pp;          const int* dst_pp = edge_pp + E_pp;
  const int* src_dp = edge_dp;          const int* dst_dp = edge_dp + E_dp;
  const int* src_cp = edge_cp;          const int* dst_cp = edge_cp + E_cp;

  // ---------------- workspace layout (floats), ~67 MB peak
  float* ws = (float*)d_ws;
  size_t off = 0;
  auto alloc = [&](size_t n) { float* p = ws + off; off += (n + 3) & ~(size_t)3; return p; };
  int maxN = NP > ND ? NP : ND; if (NC > maxN) maxN = NC;
  int emax = E_pp + NP; if (E_dp > emax) emax = E_dp; if (E_cp > emax) emax = E_cp;

  float* xp  = alloc((size_t)NP * HDIM);
  float* xd  = alloc((size_t)ND * HDIM);
  float* xc  = alloc((size_t)NC * HDIM);
  float* xdn = alloc((size_t)ND * HDIM);
  float* xcn = alloc((size_t)NC * HDIM);
  size_t scratch0 = off;                       // reused by MLP head
  float* Hp  = alloc((size_t)NP * HDIM);
  float* Hd  = alloc((size_t)ND * HDIM);
  float* outb = alloc((size_t)NP * HDIM);
  float* als = alloc(maxN);
  float* ald = alloc(maxN);
  float* mb  = alloc(maxN);
  float* den = alloc(maxN);
  float* ebuf = alloc(emax);
  (void)ws_size; (void)n_in; (void)out_size;

  GatBufs gb{Hp, Hd, als, ald, mb, den, ebuf, outb};

  const float* cur_p = prot_emb;
  const float* cur_d = drug_emb;
  const float* cur_c = cell_emb;
  for (int l = 0; l < L; ++l) {
    const int WOFF = l * HDIM * HDIM, VOFF = l * HDIM;
    // p-p conv (self loops appended), l2norm -> xp
    run_gat(stream, cur_p, NP, cur_p, NP, W_pp + WOFF, as_pp + VOFF, ad_pp + VOFF, b_pp + VOFF,
            src_pp, dst_pp, E_pp, NP, gb, xp, /*l2norm*/0);
    // d-p conv: src=proteins(new xp), dst=drugs; relu -> xd
    run_gat(stream, xp, NP, cur_d, ND, W_dp + WOFF, as_dp + VOFF, ad_dp + VOFF, b_dp + VOFF,
            src_dp, dst_dp, E_dp, 0, gb, xd, /*relu*/1);
    // c-p conv: src=proteins(new xp), dst=cells; relu -> xc
    run_gat(stream, xp, NP, cur_c, NC, W_cp + WOFF, as_cp + VOFF, ad_cp + VOFF, b_cp + VOFF,
            src_cp, dst_cp, E_cp, 0, gb, xc, /*relu*/1);
    cur_p = xp; cur_d = xd; cur_c = xc;
  }

  // ---------------- head
  l2norm_bias_kernel<<<ND, 64, 0, stream>>>(xd, nullptr, xdn, ND);
  l2norm_bias_kernel<<<NC, 64, 0, stream>>>(xc, nullptr, xcn, NC);

  // MLP in chunks; h1/h2 reuse the (now free) graph-phase scratch region
  const int CH = 2048;
  float* h1 = ws + scratch0;                       // CH*1536
  float* h2 = h1 + (size_t)CH * 1536;              // CH*512
  float* outp = (float*)d_out;
  for (int c0 = 0; c0 < B; c0 += CH) {
    int M = (B - c0) < CH ? (B - c0) : CH;
    {
      dim3 g(cdiv(1536, BN), cdiv(M, BM));
      gemm_hid<<<g, 256, 0, stream>>>(xdn, xcn, drug1, drug2, cellb, W1, b1, h1, c0, M, 1536);
    }
    {
      dim3 g(cdiv(512, BN), cdiv(M, BM));
      gemm_ab<1><<<g, 256, 0, stream>>>(h1, W2, b2, h2, M, 512, 1536);
    }
    {
      dim3 g(1, cdiv(M, BM));
      gemm_ab<0><<<g, 256, 0, stream>>>(h2, W3, b3, outp + (size_t)c0 * 2, M, 2, 512);
    }
  }
}

// Round 3
// 3540.979 us; speedup vs baseline: 1.4332x; 1.4332x over previous
//
#include <hip/hip_runtime.h>
#include <hip/hip_bf16.h>

#define HDIM 256
#define NEG_SLOPE 0.2f

typedef __attribute__((ext_vector_type(8))) short bf16x8;
typedef __attribute__((ext_vector_type(4))) float f32x4;

__device__ inline void cvt_hilo(float x, ushort& hi, ushort& lo) {
  __hip_bfloat16 h = __float2bfloat16(x);
  hi = *(ushort*)&h;
  float r = x - __bfloat162float(h);
  __hip_bfloat16 l = __float2bfloat16(r);
  lo = *(ushort*)&l;
}

// ---------------------------------------------------------------- utilities
__global__ void fillf_kernel(float* __restrict__ p, float v, int n) {
  int i = blockIdx.x * blockDim.x + threadIdx.x;
  if (i < n) p[i] = v;
}

// ---------------------------------------------------------------- MFMA GEMM (split-bf16, ~fp32 accuracy)
// C[M,N] = act(A@B + bias). A fp32 (or gathered rows), B fp32.
// A,B split into bf16 hi/lo; acc += Ah*Bh + Ah*Bl + Al*Bh  (lo*lo dropped, ~2^-18 rel err)
// 128x128 block tile, BK=32, 256 threads (4 waves, each 64x64).
#define TBM 128
#define TBN 128
#define TBK 32
#define APITCH 40   // ushorts per row (80B, 16B-aligned rows, ~2-way banks)
#define BPITCH 34   // ushorts per row (68B, 4B-aligned, stride 17 dwords coprime w/32)

template <int ACT, int GATHER>
__global__ __launch_bounds__(256) void mfma_gemm(
    const float* __restrict__ A,
    const float* __restrict__ xdn, const float* __restrict__ xcn,
    const int* __restrict__ g1, const int* __restrict__ g2, const int* __restrict__ g3,
    int row0,
    const float* __restrict__ B, const float* __restrict__ bias,
    float* __restrict__ C, int M, int N, int K) {
  __shared__ __align__(16) ushort Ah[TBM][APITCH];
  __shared__ __align__(16) ushort Al[TBM][APITCH];
  __shared__ __align__(16) ushort Bh[TBN][BPITCH];
  __shared__ __align__(16) ushort Bl[TBN][BPITCH];

  const int tid = threadIdx.x;
  const int lane = tid & 63;
  const int wid = tid >> 6;            // 0..3
  const int wm = wid & 1, wn = wid >> 1;
  const int l16 = lane & 15;
  const int quad = lane >> 4;          // 0..3
  const int m0 = blockIdx.y * TBM;
  const int n0 = blockIdx.x * TBN;

  f32x4 acc[4][4];
#pragma unroll
  for (int i = 0; i < 4; ++i)
#pragma unroll
    for (int j = 0; j < 4; ++j) acc[i][j] = (f32x4){0.f, 0.f, 0.f, 0.f};

  for (int k0 = 0; k0 < K; k0 += TBK) {
    // ---- stage A tile (128 x 32 fp32 -> hi/lo bf16)
#pragma unroll
    for (int it = 0; it < 4; ++it) {
      int f = it * 256 + tid;          // 0..1023
      int m = f >> 3;                  // 0..127
      int c = (f & 7) * 4;             // 0..28
      int gm = m0 + m;
      float4 v = make_float4(0.f, 0.f, 0.f, 0.f);
      if (gm < M) {
        const float* ap;
        if (GATHER) {
          int bi = row0 + gm;
          int seg = k0 >> 8;           // BK=32 tile never crosses a 256 boundary
          int idx = (seg == 0) ? g1[bi] : (seg == 1 ? g2[bi] : g3[bi]);
          const float* tab = (seg == 2) ? xcn : xdn;
          ap = tab + (size_t)idx * HDIM + (k0 & 255) + c;
        } else {
          ap = A + (size_t)gm * K + k0 + c;
        }
        v = *(const float4*)ap;
      }
      ushort h, l;
      cvt_hilo(v.x, h, l); Ah[m][c + 0] = h; Al[m][c + 0] = l;
      cvt_hilo(v.y, h, l); Ah[m][c + 1] = h; Al[m][c + 1] = l;
      cvt_hilo(v.z, h, l); Ah[m][c + 2] = h; Al[m][c + 2] = l;
      cvt_hilo(v.w, h, l); Ah[m][c + 3] = h; Al[m][c + 3] = l;
    }
    // ---- stage B tile (32 x 128 fp32 -> transposed hi/lo bf16 [n][k])
#pragma unroll
    for (int it = 0; it < 4; ++it) {
      int f = it * 256 + tid;          // 0..1023
      int n = (f & 31) * 4;            // 0..124
      int k = f >> 5;                  // 0..31
      int gn = n0 + n;
      float4 v = make_float4(0.f, 0.f, 0.f, 0.f);
      if (gn < N) v = *(const float4*)(B + (size_t)(k0 + k) * N + gn);
      ushort h, l;
      cvt_hilo(v.x, h, l); Bh[n + 0][k] = h; Bl[n + 0][k] = l;
      cvt_hilo(v.y, h, l); Bh[n + 1][k] = h; Bl[n + 1][k] = l;
      cvt_hilo(v.z, h, l); Bh[n + 2][k] = h; Bl[n + 2][k] = l;
      cvt_hilo(v.w, h, l); Bh[n + 3][k] = h; Bl[n + 3][k] = l;
    }
    __syncthreads();

    bf16x8 a_hi[4], a_lo[4], b_hi[4], b_lo[4];
#pragma unroll
    for (int t = 0; t < 4; ++t) {
      int ar = wm * 64 + t * 16 + l16;
      a_hi[t] = *(const bf16x8*)&Ah[ar][quad * 8];
      a_lo[t] = *(const bf16x8*)&Al[ar][quad * 8];
      int br = wn * 64 + t * 16 + l16;
      union { uint u[4]; bf16x8 v; } uh, ul;
      const uint* ph = (const uint*)&Bh[br][quad * 8];
      const uint* pl = (const uint*)&Bl[br][quad * 8];
      uh.u[0] = ph[0]; uh.u[1] = ph[1]; uh.u[2] = ph[2]; uh.u[3] = ph[3];
      ul.u[0] = pl[0]; ul.u[1] = pl[1]; ul.u[2] = pl[2]; ul.u[3] = pl[3];
      b_hi[t] = uh.v; b_lo[t] = ul.v;
    }
#pragma unroll
    for (int tm = 0; tm < 4; ++tm)
#pragma unroll
      for (int tn = 0; tn < 4; ++tn) {
        acc[tm][tn] = __builtin_amdgcn_mfma_f32_16x16x32_bf16(a_hi[tm], b_hi[tn], acc[tm][tn], 0, 0, 0);
        acc[tm][tn] = __builtin_amdgcn_mfma_f32_16x16x32_bf16(a_hi[tm], b_lo[tn], acc[tm][tn], 0, 0, 0);
        acc[tm][tn] = __builtin_amdgcn_mfma_f32_16x16x32_bf16(a_lo[tm], b_hi[tn], acc[tm][tn], 0, 0, 0);
      }
    __syncthreads();
  }

  // ---- epilogue: C/D layout col=lane&15, row=quad*4+reg
#pragma unroll
  for (int tn = 0; tn < 4; ++tn) {
    int col = n0 + wn * 64 + tn * 16 + l16;
    if (col >= N) continue;
    float bv = bias ? bias[col] : 0.f;
#pragma unroll
    for (int tm = 0; tm < 4; ++tm) {
#pragma unroll
      for (int r = 0; r < 4; ++r) {
        int row = m0 + wm * 64 + tm * 16 + quad * 4 + r;
        if (row >= M) continue;
        float v = acc[tm][tn][r] + bv;
        if (ACT == 1) v = fmaxf(v, 0.f);
        C[(size_t)row * N + col] = v;
      }
    }
  }
}

// ---------------------------------------------------------------- row dot: out[r] = H[r,:] . a
__global__ __launch_bounds__(64) void rowdot_kernel(
    const float* __restrict__ H, const float* __restrict__ a,
    float* __restrict__ out, int n) {
  int row = blockIdx.x;
  if (row >= n) return;
  int lane = threadIdx.x;
  const float* h = H + (size_t)row * HDIM;
  float s = 0.f;
#pragma unroll
  for (int u = 0; u < 4; ++u) {
    int c = lane + u * 64;
    s += h[c] * a[c];
  }
#pragma unroll
  for (int off = 32; off; off >>= 1) s += __shfl_down(s, off);
  if (lane == 0) out[row] = s;
}

// ---------------------------------------------------------------- edge passes
__device__ inline void atomicMaxF(float* addr, float val) {
  if (val >= 0.f)
    atomicMax((int*)addr, __float_as_int(val));
  else
    atomicMin((unsigned int*)addr, __float_as_uint(val));
}

// pass1: e = leaky_relu(als[src]+ald[dst]); store e; Mg = max over ALL edges
// (softmax per dst is invariant to any per-dst constant -> a global constant works;
//  e-spread is O(10) so exp(e-Mg) cannot over/underflow)
__global__ __launch_bounds__(256) void edge_pass1_kernel(
    const int* __restrict__ src, const int* __restrict__ dst, int E, int nloops,
    const float* __restrict__ als, const float* __restrict__ ald,
    float* __restrict__ ebuf, float* __restrict__ Mg) {
  int i = blockIdx.x * 256 + threadIdx.x;
  int tot = E + nloops;
  float v = -1e30f;
  if (i < tot) {
    int s_, d_;
    if (i < E) { s_ = src[i]; d_ = dst[i]; }
    else       { s_ = d_ = i - E; }
    float e = als[s_] + ald[d_];
    e = (e > 0.f) ? e : NEG_SLOPE * e;
    ebuf[i] = e;
    v = e;
  }
#pragma unroll
  for (int off = 32; off; off >>= 1) v = fmaxf(v, __shfl_down(v, off));
  __shared__ float wmax[4];
  if ((threadIdx.x & 63) == 0) wmax[threadIdx.x >> 6] = v;
  __syncthreads();
  if (threadIdx.x == 0) {
    float b = fmaxf(fmaxf(wmax[0], wmax[1]), fmaxf(wmax[2], wmax[3]));
    atomicMaxF(Mg, b);
  }
}

// pass2: ex = exp(e - Mg); store ex; denom[dst] += ex
__global__ void edge_pass2_kernel(const int* __restrict__ dst, int E, int nloops,
                                  const float* __restrict__ Mg,
                                  float* __restrict__ ebuf, float* __restrict__ denom) {
  int i = blockIdx.x * blockDim.x + threadIdx.x;
  int tot = E + nloops;
  if (i >= tot) return;
  int d_ = (i < E) ? dst[i] : (i - E);
  float ex = __expf(ebuf[i] - Mg[0]);
  ebuf[i] = ex;
  atomicAdd(&denom[d_], ex);
}

// pass3: out[dst,:] += (ex/denom[dst]) * H[src,:]   (one wave per edge)
__global__ __launch_bounds__(256) void edge_aggregate_kernel(
    const int* __restrict__ src, const int* __restrict__ dst, int E, int nloops,
    const float* __restrict__ ebuf, const float* __restrict__ denom,
    const float* __restrict__ H, float* __restrict__ out) {
  int e = blockIdx.x * 4 + (threadIdx.x >> 6);
  int lane = threadIdx.x & 63;
  int tot = E + nloops;
  if (e >= tot) return;
  int s_, d_;
  if (e < E) { s_ = src[e]; d_ = dst[e]; }
  else       { s_ = d_ = e - E; }
  float coef = ebuf[e] / (denom[d_] + 1e-16f);
  const float* h = H + (size_t)s_ * HDIM;
  float* o = out + (size_t)d_ * HDIM;
#pragma unroll
  for (int u = 0; u < 4; ++u) {
    int c = lane + u * 64;
    atomicAdd(&o[c], coef * h[c]);
  }
}

// ---------------------------------------------------------------- finalize
__global__ __launch_bounds__(64) void l2norm_bias_kernel(
    const float* __restrict__ acc, const float* __restrict__ bias,
    float* __restrict__ xout, int n) {
  int row = blockIdx.x;
  if (row >= n) return;
  int lane = threadIdx.x;
  float v[4];
  float ss = 0.f;
#pragma unroll
  for (int u = 0; u < 4; ++u) {
    int c = lane + u * 64;
    float t = acc[(size_t)row * HDIM + c];
    if (bias) t += bias[c];
    v[u] = t;
    ss += t * t;
  }
#pragma unroll
  for (int off = 32; off; off >>= 1) ss += __shfl_xor(ss, off);
  float sc = 1.0f / fmaxf(sqrtf(ss), 1e-12f);
#pragma unroll
  for (int u = 0; u < 4; ++u) {
    int c = lane + u * 64;
    xout[(size_t)row * HDIM + c] = v[u] * sc;
  }
}

__global__ void relu_bias_kernel(const float* __restrict__ acc, const float* __restrict__ bias,
                                 float* __restrict__ xout, int total) {
  int i = blockIdx.x * blockDim.x + threadIdx.x;
  if (i >= total) return;
  int c = i & (HDIM - 1);
  xout[i] = fmaxf(acc[i] + bias[c], 0.f);
}

// out[i,0:2] = h2[i,:] @ W3 + b3   (one wave per row)
__global__ __launch_bounds__(256) void head3_kernel(
    const float* __restrict__ h2, const float* __restrict__ W3, const float* __restrict__ b3,
    float* __restrict__ out, int M, int K) {
  int i = blockIdx.x * 4 + (threadIdx.x >> 6);
  int lane = threadIdx.x & 63;
  if (i >= M) return;
  float s0 = 0.f, s1 = 0.f;
  for (int k = lane; k < K; k += 64) {
    float h = h2[(size_t)i * K + k];
    s0 += h * W3[k * 2 + 0];
    s1 += h * W3[k * 2 + 1];
  }
#pragma unroll
  for (int off = 32; off; off >>= 1) {
    s0 += __shfl_down(s0, off);
    s1 += __shfl_down(s1, off);
  }
  if (lane == 0) {
    out[(size_t)i * 2 + 0] = s0 + b3[0];
    out[(size_t)i * 2 + 1] = s1 + b3[1];
  }
}

// ---------------------------------------------------------------- host side
static inline int cdiv(int a, int b) { return (a + b - 1) / b; }

struct GatBufs {
  float *Hsrc, *Hdst, *als, *ald, *Mg, *den, *ebuf, *out;
};

static void run_gat(hipStream_t stream,
                    const float* Xsrc, int Ns, const float* Xdst, int Nd,
                    const float* W, const float* asrc, const float* adst, const float* bias,
                    const int* esrc, const int* edst, int E, int nloops,
                    const GatBufs& b, float* xout, int act /*0=l2norm,1=relu*/) {
  // h = x @ W  (split-bf16 MFMA)
  {
    dim3 g(cdiv(HDIM, TBN), cdiv(Ns, TBM));
    mfma_gemm<0, 0><<<g, 256, 0, stream>>>(Xsrc, nullptr, nullptr, nullptr, nullptr, nullptr, 0,
                                           W, nullptr, b.Hsrc, Ns, HDIM, HDIM);
  }
  const float* Hd = b.Hsrc;
  if (Xdst != Xsrc) {
    dim3 g(cdiv(HDIM, TBN), cdiv(Nd, TBM));
    mfma_gemm<0, 0><<<g, 256, 0, stream>>>(Xdst, nullptr, nullptr, nullptr, nullptr, nullptr, 0,
                                           W, nullptr, b.Hdst, Nd, HDIM, HDIM);
    Hd = b.Hdst;
  }
  rowdot_kernel<<<Ns, 64, 0, stream>>>(b.Hsrc, asrc, b.als, Ns);
  rowdot_kernel<<<Nd, 64, 0, stream>>>(Hd, adst, b.ald, Nd);
  fillf_kernel<<<1, 64, 0, stream>>>(b.Mg, -1e30f, 1);
  fillf_kernel<<<cdiv(Nd, 256), 256, 0, stream>>>(b.den, 0.f, Nd);
  fillf_kernel<<<cdiv(Nd * HDIM, 256), 256, 0, stream>>>(b.out, 0.f, Nd * HDIM);
  int tot = E + nloops;
  edge_pass1_kernel<<<cdiv(tot, 256), 256, 0, stream>>>(esrc, edst, E, nloops, b.als, b.ald, b.ebuf, b.Mg);
  edge_pass2_kernel<<<cdiv(tot, 256), 256, 0, stream>>>(edst, E, nloops, b.Mg, b.ebuf, b.den);
  edge_aggregate_kernel<<<cdiv(tot, 4), 256, 0, stream>>>(esrc, edst, E, nloops, b.ebuf, b.den, b.Hsrc, b.out);
  if (act == 0)
    l2norm_bias_kernel<<<Nd, 64, 0, stream>>>(b.out, bias, xout, Nd);
  else
    relu_bias_kernel<<<cdiv(Nd * HDIM, 256), 256, 0, stream>>>(b.out, bias, xout, Nd * HDIM);
}

extern "C" void kernel_launch(void* const* d_in, const int* in_sizes, int n_in,
                              void* d_out, int out_size, void* d_ws, size_t ws_size,
                              hipStream_t stream) {
  const float* drug_emb = (const float*)d_in[0];
  const float* prot_emb = (const float*)d_in[1];
  const float* cell_emb = (const float*)d_in[2];
  const float* W_pp = (const float*)d_in[3];
  const float* as_pp = (const float*)d_in[4];
  const float* ad_pp = (const float*)d_in[5];
  const float* b_pp = (const float*)d_in[6];
  const float* W_dp = (const float*)d_in[7];
  const float* as_dp = (const float*)d_in[8];
  const float* ad_dp = (const float*)d_in[9];
  const float* b_dp = (const float*)d_in[10];
  const float* W_cp = (const float*)d_in[11];
  const float* as_cp = (const float*)d_in[12];
  const float* ad_cp = (const float*)d_in[13];
  const float* b_cp = (const float*)d_in[14];
  const float* W1 = (const float*)d_in[15];
  const float* b1 = (const float*)d_in[16];
  const float* W2 = (const float*)d_in[17];
  const float* b2 = (const float*)d_in[18];
  const float* W3 = (const float*)d_in[19];
  const float* b3 = (const float*)d_in[20];
  const int* edge_pp = (const int*)d_in[21];
  const int* edge_dp = (const int*)d_in[22];
  const int* edge_cp = (const int*)d_in[23];
  const int* drug1 = (const int*)d_in[24];
  const int* drug2 = (const int*)d_in[25];
  const int* cellb = (const int*)d_in[26];

  const int ND = in_sizes[0] / HDIM;   // 2000
  const int NP = in_sizes[1] / HDIM;   // 19000
  const int NC = in_sizes[2] / HDIM;   // 100
  const int L = in_sizes[3] / (HDIM * HDIM);  // 2
  const int E_pp = in_sizes[21] / 2;   // 400000
  const int E_dp = in_sizes[22] / 2;   // 60000
  const int E_cp = in_sizes[23] / 2;   // 300000
  const int B = in_sizes[24];          // 8192

  const int* src_pp = edge_pp;          const int* dst_pp = edge_pp + E_pp;
  const int* src_dp = edge_dp;          const int* dst_dp = edge_dp + E_dp;
  const int* src_cp = edge_cp;          const int* dst_cp = edge_cp + E_cp;

  // ---------------- workspace layout (floats), ~67 MB peak
  float* ws = (float*)d_ws;
  size_t off = 0;
  auto alloc = [&](size_t n) { float* p = ws + off; off += (n + 3) & ~(size_t)3; return p; };
  int maxN = NP > ND ? NP : ND; if (NC > maxN) maxN = NC;
  int emax = E_pp + NP; if (E_dp > emax) emax = E_dp; if (E_cp > emax) emax = E_cp;

  float* xp  = alloc((size_t)NP * HDIM);
  float* xd  = alloc((size_t)ND * HDIM);
  float* xc  = alloc((size_t)NC * HDIM);
  float* xdn = alloc((size_t)ND * HDIM);
  float* xcn = alloc((size_t)NC * HDIM);
  size_t scratch0 = off;                       // reused by MLP head
  float* Hp  = alloc((size_t)NP * HDIM);
  float* Hd  = alloc((size_t)ND * HDIM);
  float* outb = alloc((size_t)NP * HDIM);
  float* als = alloc(maxN);
  float* ald = alloc(maxN);
  float* Mg  = alloc(4);
  float* den = alloc(maxN);
  float* ebuf = alloc(emax);
  (void)ws_size; (void)n_in; (void)out_size;

  GatBufs gb{Hp, Hd, als, ald, Mg, den, ebuf, outb};

  const float* cur_p = prot_emb;
  const float* cur_d = drug_emb;
  const float* cur_c = cell_emb;
  for (int l = 0; l < L; ++l) {
    const int WOFF = l * HDIM * HDIM, VOFF = l * HDIM;
    run_gat(stream, cur_p, NP, cur_p, NP, W_pp + WOFF, as_pp + VOFF, ad_pp + VOFF, b_pp + VOFF,
            src_pp, dst_pp, E_pp, NP, gb, xp, /*l2norm*/0);
    run_gat(stream, xp, NP, cur_d, ND, W_dp + WOFF, as_dp + VOFF, ad_dp + VOFF, b_dp + VOFF,
            src_dp, dst_dp, E_dp, 0, gb, xd, /*relu*/1);
    run_gat(stream, xp, NP, cur_c, NC, W_cp + WOFF, as_cp + VOFF, ad_cp + VOFF, b_cp + VOFF,
            src_cp, dst_cp, E_cp, 0, gb, xc, /*relu*/1);
    cur_p = xp; cur_d = xd; cur_c = xc;
  }

  // ---------------- head
  l2norm_bias_kernel<<<ND, 64, 0, stream>>>(xd, nullptr, xdn, ND);
  l2norm_bias_kernel<<<NC, 64, 0, stream>>>(xc, nullptr, xcn, NC);

  // MLP in chunks of 4096 rows; h1/h2 reuse the (now free) graph-phase scratch
  const int CH = 4096;
  float* h1 = ws + scratch0;                       // CH*1536 = 25.2 MB
  float* h2 = h1 + (size_t)CH * 1536;              // CH*512  =  8.4 MB (total 33.6 < 43 MB scratch)
  float* outp = (float*)d_out;
  for (int c0 = 0; c0 < B; c0 += CH) {
    int M = (B - c0) < CH ? (B - c0) : CH;
    {
      dim3 g(cdiv(1536, TBN), cdiv(M, TBM));
      mfma_gemm<1, 1><<<g, 256, 0, stream>>>(nullptr, xdn, xcn, drug1, drug2, cellb, c0,
                                             W1, b1, h1, M, 1536, 768);
    }
    {
      dim3 g(cdiv(512, TBN), cdiv(M, TBM));
      mfma_gemm<1, 0><<<g, 256, 0, stream>>>(h1, nullptr, nullptr, nullptr, nullptr, nullptr, 0,
                                             W2, b2, h2, M, 512, 1536);
    }
    head3_kernel<<<cdiv(M, 4), 256, 0, stream>>>(h2, W3, b3, outp + (size_t)c0 * 2, M, 512);
  }
}

// Round 4
// 2807.937 us; speedup vs baseline: 1.8073x; 1.2611x over previous
//
#include <hip/hip_runtime.h>
#include <hip/hip_bf16.h>

#define HDIM 256
#define NEG_SLOPE 0.2f

typedef __attribute__((ext_vector_type(8))) short bf16x8;
typedef __attribute__((ext_vector_type(4))) float f32x4;

__device__ inline void cvt_hilo(float x, ushort& hi, ushort& lo) {
  __hip_bfloat16 h = __float2bfloat16(x);
  hi = *(ushort*)&h;
  float r = x - __bfloat162float(h);
  __hip_bfloat16 l = __float2bfloat16(r);
  lo = *(ushort*)&l;
}

// ---------------------------------------------------------------- utilities
__global__ void fillf_kernel(float* __restrict__ p, float v, int n) {
  int i = blockIdx.x * blockDim.x + threadIdx.x;
  if (i < n) p[i] = v;
}

// ---------------------------------------------------------------- MFMA GEMM (split-bf16, ~fp32 accuracy)
#define TBM 128
#define TBN 128
#define TBK 32
#define APITCH 40
#define BPITCH 34

template <int ACT, int GATHER>
__global__ __launch_bounds__(256) void mfma_gemm(
    const float* __restrict__ A,
    const float* __restrict__ xdn, const float* __restrict__ xcn,
    const int* __restrict__ g1, const int* __restrict__ g2, const int* __restrict__ g3,
    int row0,
    const float* __restrict__ B, const float* __restrict__ bias,
    float* __restrict__ C, int M, int N, int K) {
  __shared__ __align__(16) ushort Ah[TBM][APITCH];
  __shared__ __align__(16) ushort Al[TBM][APITCH];
  __shared__ __align__(16) ushort Bh[TBN][BPITCH];
  __shared__ __align__(16) ushort Bl[TBN][BPITCH];

  const int tid = threadIdx.x;
  const int lane = tid & 63;
  const int wid = tid >> 6;
  const int wm = wid & 1, wn = wid >> 1;
  const int l16 = lane & 15;
  const int quad = lane >> 4;
  const int m0 = blockIdx.y * TBM;
  const int n0 = blockIdx.x * TBN;

  f32x4 acc[4][4];
#pragma unroll
  for (int i = 0; i < 4; ++i)
#pragma unroll
    for (int j = 0; j < 4; ++j) acc[i][j] = (f32x4){0.f, 0.f, 0.f, 0.f};

  for (int k0 = 0; k0 < K; k0 += TBK) {
#pragma unroll
    for (int it = 0; it < 4; ++it) {
      int f = it * 256 + tid;
      int m = f >> 3;
      int c = (f & 7) * 4;
      int gm = m0 + m;
      float4 v = make_float4(0.f, 0.f, 0.f, 0.f);
      if (gm < M) {
        const float* ap;
        if (GATHER) {
          int bi = row0 + gm;
          int seg = k0 >> 8;
          int idx = (seg == 0) ? g1[bi] : (seg == 1 ? g2[bi] : g3[bi]);
          const float* tab = (seg == 2) ? xcn : xdn;
          ap = tab + (size_t)idx * HDIM + (k0 & 255) + c;
        } else {
          ap = A + (size_t)gm * K + k0 + c;
        }
        v = *(const float4*)ap;
      }
      ushort h, l;
      cvt_hilo(v.x, h, l); Ah[m][c + 0] = h; Al[m][c + 0] = l;
      cvt_hilo(v.y, h, l); Ah[m][c + 1] = h; Al[m][c + 1] = l;
      cvt_hilo(v.z, h, l); Ah[m][c + 2] = h; Al[m][c + 2] = l;
      cvt_hilo(v.w, h, l); Ah[m][c + 3] = h; Al[m][c + 3] = l;
    }
#pragma unroll
    for (int it = 0; it < 4; ++it) {
      int f = it * 256 + tid;
      int n = (f & 31) * 4;
      int k = f >> 5;
      int gn = n0 + n;
      float4 v = make_float4(0.f, 0.f, 0.f, 0.f);
      if (gn < N) v = *(const float4*)(B + (size_t)(k0 + k) * N + gn);
      ushort h, l;
      cvt_hilo(v.x, h, l); Bh[n + 0][k] = h; Bl[n + 0][k] = l;
      cvt_hilo(v.y, h, l); Bh[n + 1][k] = h; Bl[n + 1][k] = l;
      cvt_hilo(v.z, h, l); Bh[n + 2][k] = h; Bl[n + 2][k] = l;
      cvt_hilo(v.w, h, l); Bh[n + 3][k] = h; Bl[n + 3][k] = l;
    }
    __syncthreads();

    bf16x8 a_hi[4], a_lo[4], b_hi[4], b_lo[4];
#pragma unroll
    for (int t = 0; t < 4; ++t) {
      int ar = wm * 64 + t * 16 + l16;
      a_hi[t] = *(const bf16x8*)&Ah[ar][quad * 8];
      a_lo[t] = *(const bf16x8*)&Al[ar][quad * 8];
      int br = wn * 64 + t * 16 + l16;
      union { uint u[4]; bf16x8 v; } uh, ul;
      const uint* ph = (const uint*)&Bh[br][quad * 8];
      const uint* pl = (const uint*)&Bl[br][quad * 8];
      uh.u[0] = ph[0]; uh.u[1] = ph[1]; uh.u[2] = ph[2]; uh.u[3] = ph[3];
      ul.u[0] = pl[0]; ul.u[1] = pl[1]; ul.u[2] = pl[2]; ul.u[3] = pl[3];
      b_hi[t] = uh.v; b_lo[t] = ul.v;
    }
#pragma unroll
    for (int tm = 0; tm < 4; ++tm)
#pragma unroll
      for (int tn = 0; tn < 4; ++tn) {
        acc[tm][tn] = __builtin_amdgcn_mfma_f32_16x16x32_bf16(a_hi[tm], b_hi[tn], acc[tm][tn], 0, 0, 0);
        acc[tm][tn] = __builtin_amdgcn_mfma_f32_16x16x32_bf16(a_hi[tm], b_lo[tn], acc[tm][tn], 0, 0, 0);
        acc[tm][tn] = __builtin_amdgcn_mfma_f32_16x16x32_bf16(a_lo[tm], b_hi[tn], acc[tm][tn], 0, 0, 0);
      }
    __syncthreads();
  }

#pragma unroll
  for (int tn = 0; tn < 4; ++tn) {
    int col = n0 + wn * 64 + tn * 16 + l16;
    if (col >= N) continue;
    float bv = bias ? bias[col] : 0.f;
#pragma unroll
    for (int tm = 0; tm < 4; ++tm) {
#pragma unroll
      for (int r = 0; r < 4; ++r) {
        int row = m0 + wm * 64 + tm * 16 + quad * 4 + r;
        if (row >= M) continue;
        float v = acc[tm][tn][r] + bv;
        if (ACT == 1) v = fmaxf(v, 0.f);
        C[(size_t)row * N + col] = v;
      }
    }
  }
}

// ---------------------------------------------------------------- row dot
__global__ __launch_bounds__(64) void rowdot_kernel(
    const float* __restrict__ H, const float* __restrict__ a,
    float* __restrict__ out, int n) {
  int row = blockIdx.x;
  if (row >= n) return;
  int lane = threadIdx.x;
  const float* h = H + (size_t)row * HDIM;
  float s = 0.f;
#pragma unroll
  for (int u = 0; u < 4; ++u) {
    int c = lane + u * 64;
    s += h[c] * a[c];
  }
#pragma unroll
  for (int off = 32; off; off >>= 1) s += __shfl_down(s, off);
  if (lane == 0) out[row] = s;
}

// ---------------------------------------------------------------- edge passes
__device__ inline void atomicMaxF(float* addr, float val) {
  if (val >= 0.f)
    atomicMax((int*)addr, __float_as_int(val));
  else
    atomicMin((unsigned int*)addr, __float_as_uint(val));
}

// pass1: e = leaky_relu(als[src]+ald[dst]); store e; Mg = global max (block-reduced)
__global__ __launch_bounds__(256) void edge_pass1_kernel(
    const int* __restrict__ src, const int* __restrict__ dst, int E, int nloops,
    const float* __restrict__ als, const float* __restrict__ ald,
    float* __restrict__ ebuf, float* __restrict__ Mg) {
  int i = blockIdx.x * 256 + threadIdx.x;
  int tot = E + nloops;
  float v = -1e30f;
  if (i < tot) {
    int s_, d_;
    if (i < E) { s_ = src[i]; d_ = dst[i]; }
    else       { s_ = d_ = i - E; }
    float e = als[s_] + ald[d_];
    e = (e > 0.f) ? e : NEG_SLOPE * e;
    ebuf[i] = e;
    v = e;
  }
#pragma unroll
  for (int off = 32; off; off >>= 1) v = fmaxf(v, __shfl_down(v, off));
  __shared__ float wmax[4];
  if ((threadIdx.x & 63) == 0) wmax[threadIdx.x >> 6] = v;
  __syncthreads();
  if (threadIdx.x == 0) {
    float b = fmaxf(fmaxf(wmax[0], wmax[1]), fmaxf(wmax[2], wmax[3]));
    atomicMaxF(Mg, b);
  }
}

// pass2: ex = exp(e - Mg); store ex; denom[dst] += ex.
// LDS-privatized per-block denom (wave-scattered GLOBAL atomics are ~400us —
// 64 lanes hitting 64 random lines serialize; LDS atomics + coalesced merge don't).
__global__ __launch_bounds__(256) void edge_pass2_kernel(
    const int* __restrict__ dst, int E, int nloops, int Nd,
    const float* __restrict__ Mg,
    float* __restrict__ ebuf, float* __restrict__ denom) {
  extern __shared__ float sden[];   // Nd floats
  for (int i = threadIdx.x; i < Nd; i += 256) sden[i] = 0.f;
  __syncthreads();
  const float mg = Mg[0];
  int tot = E + nloops;
  for (int i = blockIdx.x * 256 + threadIdx.x; i < tot; i += gridDim.x * 256) {
    int d_ = (i < E) ? dst[i] : (i - E);
    float ex = __expf(ebuf[i] - mg);
    ebuf[i] = ex;
    atomicAdd(&sden[d_], ex);     // LDS atomic
  }
  __syncthreads();
  for (int i = threadIdx.x; i < Nd; i += 256) {
    float v = sden[i];
    if (v != 0.f) atomicAdd(&denom[i], v);   // coalesced global atomic, mostly skipped
  }
}

// pass3: out[dst,:] += (ex/denom[dst]) * H[src,:]   (one wave per edge)
__global__ __launch_bounds__(256) void edge_aggregate_kernel(
    const int* __restrict__ src, const int* __restrict__ dst, int E, int nloops,
    const float* __restrict__ ebuf, const float* __restrict__ denom,
    const float* __restrict__ H, float* __restrict__ out) {
  int e = blockIdx.x * 4 + (threadIdx.x >> 6);
  int lane = threadIdx.x & 63;
  int tot = E + nloops;
  if (e >= tot) return;
  int s_, d_;
  if (e < E) { s_ = src[e]; d_ = dst[e]; }
  else       { s_ = d_ = e - E; }
  float coef = ebuf[e] / (denom[d_] + 1e-16f);
  const float* h = H + (size_t)s_ * HDIM;
  float* o = out + (size_t)d_ * HDIM;
#pragma unroll
  for (int u = 0; u < 4; ++u) {
    int c = lane + u * 64;
    atomicAdd(&o[c], coef * h[c]);
  }
}

// ---------------------------------------------------------------- finalize
__global__ __launch_bounds__(64) void l2norm_bias_kernel(
    const float* __restrict__ acc, const float* __restrict__ bias,
    float* __restrict__ xout, int n) {
  int row = blockIdx.x;
  if (row >= n) return;
  int lane = threadIdx.x;
  float v[4];
  float ss = 0.f;
#pragma unroll
  for (int u = 0; u < 4; ++u) {
    int c = lane + u * 64;
    float t = acc[(size_t)row * HDIM + c];
    if (bias) t += bias[c];
    v[u] = t;
    ss += t * t;
  }
#pragma unroll
  for (int off = 32; off; off >>= 1) ss += __shfl_xor(ss, off);
  float sc = 1.0f / fmaxf(sqrtf(ss), 1e-12f);
#pragma unroll
  for (int u = 0; u < 4; ++u) {
    int c = lane + u * 64;
    xout[(size_t)row * HDIM + c] = v[u] * sc;
  }
}

__global__ void relu_bias_kernel(const float* __restrict__ acc, const float* __restrict__ bias,
                                 float* __restrict__ xout, int total) {
  int i = blockIdx.x * blockDim.x + threadIdx.x;
  if (i >= total) return;
  int c = i & (HDIM - 1);
  xout[i] = fmaxf(acc[i] + bias[c], 0.f);
}

// out[i,0:2] = h2[i,:] @ W3 + b3
__global__ __launch_bounds__(256) void head3_kernel(
    const float* __restrict__ h2, const float* __restrict__ W3, const float* __restrict__ b3,
    float* __restrict__ out, int M, int K) {
  int i = blockIdx.x * 4 + (threadIdx.x >> 6);
  int lane = threadIdx.x & 63;
  if (i >= M) return;
  float s0 = 0.f, s1 = 0.f;
  for (int k = lane; k < K; k += 64) {
    float h = h2[(size_t)i * K + k];
    s0 += h * W3[k * 2 + 0];
    s1 += h * W3[k * 2 + 1];
  }
#pragma unroll
  for (int off = 32; off; off >>= 1) {
    s0 += __shfl_down(s0, off);
    s1 += __shfl_down(s1, off);
  }
  if (lane == 0) {
    out[(size_t)i * 2 + 0] = s0 + b3[0];
    out[(size_t)i * 2 + 1] = s1 + b3[1];
  }
}

// ---------------------------------------------------------------- host side
static inline int cdiv(int a, int b) { return (a + b - 1) / b; }

struct GatBufs {
  float *Hsrc, *Hdst, *als, *ald, *Mg, *den, *ebuf, *out;
};

static void run_gat(hipStream_t stream,
                    const float* Xsrc, int Ns, const float* Xdst, int Nd,
                    const float* W, const float* asrc, const float* adst, const float* bias,
                    const int* esrc, const int* edst, int E, int nloops,
                    const GatBufs& b, float* xout, int act /*0=l2norm,1=relu*/) {
  {
    dim3 g(cdiv(HDIM, TBN), cdiv(Ns, TBM));
    mfma_gemm<0, 0><<<g, 256, 0, stream>>>(Xsrc, nullptr, nullptr, nullptr, nullptr, nullptr, 0,
                                           W, nullptr, b.Hsrc, Ns, HDIM, HDIM);
  }
  const float* Hd = b.Hsrc;
  if (Xdst != Xsrc) {
    dim3 g(cdiv(HDIM, TBN), cdiv(Nd, TBM));
    mfma_gemm<0, 0><<<g, 256, 0, stream>>>(Xdst, nullptr, nullptr, nullptr, nullptr, nullptr, 0,
                                           W, nullptr, b.Hdst, Nd, HDIM, HDIM);
    Hd = b.Hdst;
  }
  rowdot_kernel<<<Ns, 64, 0, stream>>>(b.Hsrc, asrc, b.als, Ns);
  rowdot_kernel<<<Nd, 64, 0, stream>>>(Hd, adst, b.ald, Nd);
  fillf_kernel<<<1, 64, 0, stream>>>(b.Mg, -1e30f, 1);
  fillf_kernel<<<cdiv(Nd, 256), 256, 0, stream>>>(b.den, 0.f, Nd);
  fillf_kernel<<<cdiv(Nd * HDIM, 256), 256, 0, stream>>>(b.out, 0.f, Nd * HDIM);
  int tot = E + nloops;
  edge_pass1_kernel<<<cdiv(tot, 256), 256, 0, stream>>>(esrc, edst, E, nloops, b.als, b.ald, b.ebuf, b.Mg);
  {
    int nb = cdiv(tot, 256); if (nb > 512) nb = 512;
    size_t lds = (size_t)Nd * sizeof(float);
    edge_pass2_kernel<<<nb, 256, lds, stream>>>(edst, E, nloops, Nd, b.Mg, b.ebuf, b.den);
  }
  edge_aggregate_kernel<<<cdiv(tot, 4), 256, 0, stream>>>(esrc, edst, E, nloops, b.ebuf, b.den, b.Hsrc, b.out);
  if (act == 0)
    l2norm_bias_kernel<<<Nd, 64, 0, stream>>>(b.out, bias, xout, Nd);
  else
    relu_bias_kernel<<<cdiv(Nd * HDIM, 256), 256, 0, stream>>>(b.out, bias, xout, Nd * HDIM);
}

extern "C" void kernel_launch(void* const* d_in, const int* in_sizes, int n_in,
                              void* d_out, int out_size, void* d_ws, size_t ws_size,
                              hipStream_t stream) {
  const float* drug_emb = (const float*)d_in[0];
  const float* prot_emb = (const float*)d_in[1];
  const float* cell_emb = (const float*)d_in[2];
  const float* W_pp = (const float*)d_in[3];
  const float* as_pp = (const float*)d_in[4];
  const float* ad_pp = (const float*)d_in[5];
  const float* b_pp = (const float*)d_in[6];
  const float* W_dp = (const float*)d_in[7];
  const float* as_dp = (const float*)d_in[8];
  const float* ad_dp = (const float*)d_in[9];
  const float* b_dp = (const float*)d_in[10];
  const float* W_cp = (const float*)d_in[11];
  const float* as_cp = (const float*)d_in[12];
  const float* ad_cp = (const float*)d_in[13];
  const float* b_cp = (const float*)d_in[14];
  const float* W1 = (const float*)d_in[15];
  const float* b1 = (const float*)d_in[16];
  const float* W2 = (const float*)d_in[17];
  const float* b2 = (const float*)d_in[18];
  const float* W3 = (const float*)d_in[19];
  const float* b3 = (const float*)d_in[20];
  const int* edge_pp = (const int*)d_in[21];
  const int* edge_dp = (const int*)d_in[22];
  const int* edge_cp = (const int*)d_in[23];
  const int* drug1 = (const int*)d_in[24];
  const int* drug2 = (const int*)d_in[25];
  const int* cellb = (const int*)d_in[26];

  const int ND = in_sizes[0] / HDIM;
  const int NP = in_sizes[1] / HDIM;
  const int NC = in_sizes[2] / HDIM;
  const int L = in_sizes[3] / (HDIM * HDIM);
  const int E_pp = in_sizes[21] / 2;
  const int E_dp = in_sizes[22] / 2;
  const int E_cp = in_sizes[23] / 2;
  const int B = in_sizes[24];

  const int* src_pp = edge_pp;          const int* dst_pp = edge_pp + E_pp;
  const int* src_dp = edge_dp;          const int* dst_dp = edge_dp + E_dp;
  const int* src_cp = edge_cp;          const int* dst_cp = edge_cp + E_cp;

  float* ws = (float*)d_ws;
  size_t off = 0;
  auto alloc = [&](size_t n) { float* p = ws + off; off += (n + 3) & ~(size_t)3; return p; };
  int maxN = NP > ND ? NP : ND; if (NC > maxN) maxN = NC;
  int emax = E_pp + NP; if (E_dp > emax) emax = E_dp; if (E_cp > emax) emax = E_cp;

  float* xp  = alloc((size_t)NP * HDIM);
  float* xd  = alloc((size_t)ND * HDIM);
  float* xc  = alloc((size_t)NC * HDIM);
  float* xdn = alloc((size_t)ND * HDIM);
  float* xcn = alloc((size_t)NC * HDIM);
  size_t scratch0 = off;
  float* Hp  = alloc((size_t)NP * HDIM);
  float* Hd  = alloc((size_t)ND * HDIM);
  float* outb = alloc((size_t)NP * HDIM);
  float* als = alloc(maxN);
  float* ald = alloc(maxN);
  float* Mg  = alloc(4);
  float* den = alloc(maxN);
  float* ebuf = alloc(emax);
  (void)ws_size; (void)n_in; (void)out_size;

  GatBufs gb{Hp, Hd, als, ald, Mg, den, ebuf, outb};

  const float* cur_p = prot_emb;
  const float* cur_d = drug_emb;
  const float* cur_c = cell_emb;
  for (int l = 0; l < L; ++l) {
    const int WOFF = l * HDIM * HDIM, VOFF = l * HDIM;
    run_gat(stream, cur_p, NP, cur_p, NP, W_pp + WOFF, as_pp + VOFF, ad_pp + VOFF, b_pp + VOFF,
            src_pp, dst_pp, E_pp, NP, gb, xp, /*l2norm*/0);
    run_gat(stream, xp, NP, cur_d, ND, W_dp + WOFF, as_dp + VOFF, ad_dp + VOFF, b_dp + VOFF,
            src_dp, dst_dp, E_dp, 0, gb, xd, /*relu*/1);
    run_gat(stream, xp, NP, cur_c, NC, W_cp + WOFF, as_cp + VOFF, ad_cp + VOFF, b_cp + VOFF,
            src_cp, dst_cp, E_cp, 0, gb, xc, /*relu*/1);
    cur_p = xp; cur_d = xd; cur_c = xc;
  }

  l2norm_bias_kernel<<<ND, 64, 0, stream>>>(xd, nullptr, xdn, ND);
  l2norm_bias_kernel<<<NC, 64, 0, stream>>>(xc, nullptr, xcn, NC);

  const int CH = 4096;
  float* h1 = ws + scratch0;
  float* h2 = h1 + (size_t)CH * 1536;
  float* outp = (float*)d_out;
  for (int c0 = 0; c0 < B; c0 += CH) {
    int M = (B - c0) < CH ? (B - c0) : CH;
    {
      dim3 g(cdiv(1536, TBN), cdiv(M, TBM));
      mfma_gemm<1, 1><<<g, 256, 0, stream>>>(nullptr, xdn, xcn, drug1, drug2, cellb, c0,
                                             W1, b1, h1, M, 1536, 768);
    }
    {
      dim3 g(cdiv(512, TBN), cdiv(M, TBM));
      mfma_gemm<1, 0><<<g, 256, 0, stream>>>(h1, nullptr, nullptr, nullptr, nullptr, nullptr, 0,
                                             W2, b2, h2, M, 512, 1536);
    }
    head3_kernel<<<cdiv(M, 4), 256, 0, stream>>>(h2, W3, b3, outp + (size_t)c0 * 2, M, 512);
  }
}

// Round 5
// 2004.354 us; speedup vs baseline: 2.5319x; 1.4009x over previous
//
#include <hip/hip_runtime.h>
#include <hip/hip_bf16.h>

#define HDIM 256
#define NEG_SLOPE 0.2f
#define NB 128          // blocks for hist/scatter (must match both)
#define CS 128          // sorted-edge positions per wave in aggregate

typedef __attribute__((ext_vector_type(8))) short bf16x8;
typedef __attribute__((ext_vector_type(4))) float f32x4;

__device__ inline void cvt_hilo(float x, ushort& hi, ushort& lo) {
  __hip_bfloat16 h = __float2bfloat16(x);
  hi = *(ushort*)&h;
  float r = x - __bfloat162float(h);
  __hip_bfloat16 l = __float2bfloat16(r);
  lo = *(ushort*)&l;
}

// ---------------------------------------------------------------- utilities
__global__ void fillf_kernel(float* __restrict__ p, float v, int n) {
  int i = blockIdx.x * blockDim.x + threadIdx.x;
  if (i < n) p[i] = v;
}

// ---------------------------------------------------------------- MFMA GEMM (split-bf16, ~fp32 accuracy)
#define TBM 128
#define TBN 128
#define TBK 32
#define APITCH 40
#define BPITCH 34

template <int ACT, int GATHER>
__global__ __launch_bounds__(256) void mfma_gemm(
    const float* __restrict__ A,
    const float* __restrict__ xdn, const float* __restrict__ xcn,
    const int* __restrict__ g1, const int* __restrict__ g2, const int* __restrict__ g3,
    int row0,
    const float* __restrict__ B, const float* __restrict__ bias,
    float* __restrict__ C, int M, int N, int K) {
  __shared__ __align__(16) ushort Ah[TBM][APITCH];
  __shared__ __align__(16) ushort Al[TBM][APITCH];
  __shared__ __align__(16) ushort Bh[TBN][BPITCH];
  __shared__ __align__(16) ushort Bl[TBN][BPITCH];

  const int tid = threadIdx.x;
  const int lane = tid & 63;
  const int wid = tid >> 6;
  const int wm = wid & 1, wn = wid >> 1;
  const int l16 = lane & 15;
  const int quad = lane >> 4;
  const int m0 = blockIdx.y * TBM;
  const int n0 = blockIdx.x * TBN;

  f32x4 acc[4][4];
#pragma unroll
  for (int i = 0; i < 4; ++i)
#pragma unroll
    for (int j = 0; j < 4; ++j) acc[i][j] = (f32x4){0.f, 0.f, 0.f, 0.f};

  for (int k0 = 0; k0 < K; k0 += TBK) {
#pragma unroll
    for (int it = 0; it < 4; ++it) {
      int f = it * 256 + tid;
      int m = f >> 3;
      int c = (f & 7) * 4;
      int gm = m0 + m;
      float4 v = make_float4(0.f, 0.f, 0.f, 0.f);
      if (gm < M) {
        const float* ap;
        if (GATHER) {
          int bi = row0 + gm;
          int seg = k0 >> 8;
          int idx = (seg == 0) ? g1[bi] : (seg == 1 ? g2[bi] : g3[bi]);
          const float* tab = (seg == 2) ? xcn : xdn;
          ap = tab + (size_t)idx * HDIM + (k0 & 255) + c;
        } else {
          ap = A + (size_t)gm * K + k0 + c;
        }
        v = *(const float4*)ap;
      }
      ushort h, l;
      cvt_hilo(v.x, h, l); Ah[m][c + 0] = h; Al[m][c + 0] = l;
      cvt_hilo(v.y, h, l); Ah[m][c + 1] = h; Al[m][c + 1] = l;
      cvt_hilo(v.z, h, l); Ah[m][c + 2] = h; Al[m][c + 2] = l;
      cvt_hilo(v.w, h, l); Ah[m][c + 3] = h; Al[m][c + 3] = l;
    }
#pragma unroll
    for (int it = 0; it < 4; ++it) {
      int f = it * 256 + tid;
      int n = (f & 31) * 4;
      int k = f >> 5;
      int gn = n0 + n;
      float4 v = make_float4(0.f, 0.f, 0.f, 0.f);
      if (gn < N) v = *(const float4*)(B + (size_t)(k0 + k) * N + gn);
      ushort h, l;
      cvt_hilo(v.x, h, l); Bh[n + 0][k] = h; Bl[n + 0][k] = l;
      cvt_hilo(v.y, h, l); Bh[n + 1][k] = h; Bl[n + 1][k] = l;
      cvt_hilo(v.z, h, l); Bh[n + 2][k] = h; Bl[n + 2][k] = l;
      cvt_hilo(v.w, h, l); Bh[n + 3][k] = h; Bl[n + 3][k] = l;
    }
    __syncthreads();

    bf16x8 a_hi[4], a_lo[4], b_hi[4], b_lo[4];
#pragma unroll
    for (int t = 0; t < 4; ++t) {
      int ar = wm * 64 + t * 16 + l16;
      a_hi[t] = *(const bf16x8*)&Ah[ar][quad * 8];
      a_lo[t] = *(const bf16x8*)&Al[ar][quad * 8];
      int br = wn * 64 + t * 16 + l16;
      union { uint u[4]; bf16x8 v; } uh, ul;
      const uint* ph = (const uint*)&Bh[br][quad * 8];
      const uint* pl = (const uint*)&Bl[br][quad * 8];
      uh.u[0] = ph[0]; uh.u[1] = ph[1]; uh.u[2] = ph[2]; uh.u[3] = ph[3];
      ul.u[0] = pl[0]; ul.u[1] = pl[1]; ul.u[2] = pl[2]; ul.u[3] = pl[3];
      b_hi[t] = uh.v; b_lo[t] = ul.v;
    }
#pragma unroll
    for (int tm = 0; tm < 4; ++tm)
#pragma unroll
      for (int tn = 0; tn < 4; ++tn) {
        acc[tm][tn] = __builtin_amdgcn_mfma_f32_16x16x32_bf16(a_hi[tm], b_hi[tn], acc[tm][tn], 0, 0, 0);
        acc[tm][tn] = __builtin_amdgcn_mfma_f32_16x16x32_bf16(a_hi[tm], b_lo[tn], acc[tm][tn], 0, 0, 0);
        acc[tm][tn] = __builtin_amdgcn_mfma_f32_16x16x32_bf16(a_lo[tm], b_hi[tn], acc[tm][tn], 0, 0, 0);
      }
    __syncthreads();
  }

#pragma unroll
  for (int tn = 0; tn < 4; ++tn) {
    int col = n0 + wn * 64 + tn * 16 + l16;
    if (col >= N) continue;
    float bv = bias ? bias[col] : 0.f;
#pragma unroll
    for (int tm = 0; tm < 4; ++tm) {
#pragma unroll
      for (int r = 0; r < 4; ++r) {
        int row = m0 + wm * 64 + tm * 16 + quad * 4 + r;
        if (row >= M) continue;
        float v = acc[tm][tn][r] + bv;
        if (ACT == 1) v = fmaxf(v, 0.f);
        C[(size_t)row * N + col] = v;
      }
    }
  }
}

// ---------------------------------------------------------------- row dot
__global__ __launch_bounds__(64) void rowdot_kernel(
    const float* __restrict__ H, const float* __restrict__ a,
    float* __restrict__ out, int n) {
  int row = blockIdx.x;
  if (row >= n) return;
  int lane = threadIdx.x;
  const float* h = H + (size_t)row * HDIM;
  float s = 0.f;
#pragma unroll
  for (int u = 0; u < 4; ++u) {
    int c = lane + u * 64;
    s += h[c] * a[c];
  }
#pragma unroll
  for (int off = 32; off; off >>= 1) s += __shfl_down(s, off);
  if (lane == 0) out[row] = s;
}

// ---------------------------------------------------------------- counting sort by dst (build once per edge list)
// Edges synthesized: i<E -> (src[i],dst[i]); i>=E -> self-loop (i-E, i-E).
__global__ __launch_bounds__(256) void hist_kernel(
    const int* __restrict__ src, const int* __restrict__ dst, int E, int nloops,
    int Nd, int* __restrict__ offs /*[Nd*NB]*/) {
  extern __shared__ int bins[];
  int tot = E + nloops;
  int chunk = (tot + NB - 1) / NB;
  int b = blockIdx.x;
  int s0 = b * chunk, s1 = min(s0 + chunk, tot);
  for (int i = threadIdx.x; i < Nd; i += 256) bins[i] = 0;
  __syncthreads();
  for (int i = s0 + threadIdx.x; i < s1; i += 256) {
    int d = (i < E) ? dst[i] : (i - E);
    atomicAdd(&bins[d], 1);
  }
  __syncthreads();
  for (int i = threadIdx.x; i < Nd; i += 256) offs[(size_t)i * NB + b] = bins[i];
}

// per-bin exclusive scan across the NB block-counts; binsum[d] = total
__global__ __launch_bounds__(256) void scan_bins_kernel(
    int* __restrict__ offs, int* __restrict__ binsum, int Nd) {
  int d = blockIdx.x * 4 + (threadIdx.x >> 6);
  if (d >= Nd) return;
  int lane = threadIdx.x & 63;
  int* p = offs + (size_t)d * NB;
  int v0 = p[2 * lane], v1 = p[2 * lane + 1];
  int s = v0 + v1;
  int t = s;
#pragma unroll
  for (int o = 1; o < 64; o <<= 1) { int u = __shfl_up(t, o); if (lane >= o) t += u; }
  int excl = t - s;
  p[2 * lane] = excl;
  p[2 * lane + 1] = excl + v0;
  if (lane == 63) binsum[d] = t;
}

// exclusive scan of binsum -> base (single block)
__global__ __launch_bounds__(256) void scan_base_kernel(
    const int* __restrict__ binsum, int* __restrict__ base, int Nd) {
  __shared__ int wsum[4];
  __shared__ int carry;
  if (threadIdx.x == 0) carry = 0;
  __syncthreads();
  int lane = threadIdx.x & 63, w = threadIdx.x >> 6;
  for (int t0 = 0; t0 < Nd; t0 += 256) {
    int i = t0 + threadIdx.x;
    int v = (i < Nd) ? binsum[i] : 0;
    int t = v;
#pragma unroll
    for (int o = 1; o < 64; o <<= 1) { int u = __shfl_up(t, o); if (lane >= o) t += u; }
    if (lane == 63) wsum[w] = t;
    __syncthreads();
    int add = carry;
    for (int k = 0; k < w; ++k) add += wsum[k];
    if (i < Nd) base[i] = t - v + add;
    __syncthreads();
    if (threadIdx.x == 0) carry += wsum[0] + wsum[1] + wsum[2] + wsum[3];
    __syncthreads();
  }
}

// scatter edges to sorted position; sd[pos] = (src,dst)
__global__ __launch_bounds__(256) void scatter_kernel(
    const int* __restrict__ src, const int* __restrict__ dst, int E, int nloops,
    int Nd, const int* __restrict__ offs, const int* __restrict__ base,
    int2* __restrict__ sd) {
  extern __shared__ int bins[];
  int tot = E + nloops;
  int chunk = (tot + NB - 1) / NB;
  int b = blockIdx.x;
  int s0 = b * chunk, s1 = min(s0 + chunk, tot);
  for (int i = threadIdx.x; i < Nd; i += 256) bins[i] = 0;
  __syncthreads();
  for (int i = s0 + threadIdx.x; i < s1; i += 256) {
    int s_, d_;
    if (i < E) { s_ = src[i]; d_ = dst[i]; }
    else       { s_ = d_ = i - E; }
    int local = atomicAdd(&bins[d_], 1);
    int pos = base[d_] + offs[(size_t)d_ * NB + b] + local;
    sd[pos] = make_int2(s_, d_);
  }
}

// ---------------------------------------------------------------- edge passes (sorted order)
__device__ inline void atomicMaxF(float* addr, float val) {
  if (val >= 0.f)
    atomicMax((int*)addr, __float_as_int(val));
  else
    atomicMin((unsigned int*)addr, __float_as_uint(val));
}

// pass1: e = leaky_relu(als[src]+ald[dst]); Mg = global max (block-reduced)
__global__ __launch_bounds__(256) void edge_pass1_kernel(
    const int2* __restrict__ sd, int tot,
    const float* __restrict__ als, const float* __restrict__ ald,
    float* __restrict__ ebuf, float* __restrict__ Mg) {
  int i = blockIdx.x * 256 + threadIdx.x;
  float v = -1e30f;
  if (i < tot) {
    int2 e = sd[i];
    float x = als[e.x] + ald[e.y];
    x = (x > 0.f) ? x : NEG_SLOPE * x;
    ebuf[i] = x;
    v = x;
  }
#pragma unroll
  for (int off = 32; off; off >>= 1) v = fmaxf(v, __shfl_down(v, off));
  __shared__ float wmax[4];
  if ((threadIdx.x & 63) == 0) wmax[threadIdx.x >> 6] = v;
  __syncthreads();
  if (threadIdx.x == 0) {
    float b = fmaxf(fmaxf(wmax[0], wmax[1]), fmaxf(wmax[2], wmax[3]));
    atomicMaxF(Mg, b);
  }
}

// pass2: ex = exp(e - Mg); denom[dst] += ex  (LDS-privatized)
__global__ __launch_bounds__(256) void edge_pass2_kernel(
    const int2* __restrict__ sd, int tot, int Nd,
    const float* __restrict__ Mg,
    float* __restrict__ ebuf, float* __restrict__ denom) {
  extern __shared__ float sden[];
  for (int i = threadIdx.x; i < Nd; i += 256) sden[i] = 0.f;
  __syncthreads();
  const float mg = Mg[0];
  for (int i = blockIdx.x * 256 + threadIdx.x; i < tot; i += gridDim.x * 256) {
    float ex = __expf(ebuf[i] - mg);
    ebuf[i] = ex;
    atomicAdd(&sden[sd[i].y], ex);
  }
  __syncthreads();
  for (int i = threadIdx.x; i < Nd; i += 256) {
    float v = sden[i];
    if (v != 0.f) atomicAdd(&denom[i], v);
  }
}

// pass3: segmented reduction over dst-sorted edges; one flush per segment
// (replaces per-edge atomics: 429 MB atomic RMW -> ~25 MB)
__global__ __launch_bounds__(256) void edge_aggregate_csr(
    const int2* __restrict__ sd, int tot,
    const float* __restrict__ ebuf, const float* __restrict__ denom,
    const float* __restrict__ H, float* __restrict__ out) {
  int w = blockIdx.x * 4 + (threadIdx.x >> 6);
  int lane = threadIdx.x & 63;
  int s0 = w * CS;
  if (s0 >= tot) return;
  int s1 = min(s0 + CS, tot);
  float4 acc = make_float4(0.f, 0.f, 0.f, 0.f);
  int cur = sd[s0].y;
  for (int i = s0; i < s1; ++i) {
    int2 e = sd[i];
    if (e.y != cur) {
      float* o = out + (size_t)cur * HDIM + lane * 4;
      atomicAdd(o + 0, acc.x); atomicAdd(o + 1, acc.y);
      atomicAdd(o + 2, acc.z); atomicAdd(o + 3, acc.w);
      acc = make_float4(0.f, 0.f, 0.f, 0.f);
      cur = e.y;
    }
    float coef = ebuf[i] / (denom[e.y] + 1e-16f);
    float4 h = *(const float4*)(H + (size_t)e.x * HDIM + lane * 4);
    acc.x += coef * h.x; acc.y += coef * h.y;
    acc.z += coef * h.z; acc.w += coef * h.w;
  }
  float* o = out + (size_t)cur * HDIM + lane * 4;
  atomicAdd(o + 0, acc.x); atomicAdd(o + 1, acc.y);
  atomicAdd(o + 2, acc.z); atomicAdd(o + 3, acc.w);
}

// ---------------------------------------------------------------- finalize
__global__ __launch_bounds__(64) void l2norm_bias_kernel(
    const float* __restrict__ acc, const float* __restrict__ bias,
    float* __restrict__ xout, int n) {
  int row = blockIdx.x;
  if (row >= n) return;
  int lane = threadIdx.x;
  float v[4];
  float ss = 0.f;
#pragma unroll
  for (int u = 0; u < 4; ++u) {
    int c = lane + u * 64;
    float t = acc[(size_t)row * HDIM + c];
    if (bias) t += bias[c];
    v[u] = t;
    ss += t * t;
  }
#pragma unroll
  for (int off = 32; off; off >>= 1) ss += __shfl_xor(ss, off);
  float sc = 1.0f / fmaxf(sqrtf(ss), 1e-12f);
#pragma unroll
  for (int u = 0; u < 4; ++u) {
    int c = lane + u * 64;
    xout[(size_t)row * HDIM + c] = v[u] * sc;
  }
}

__global__ void relu_bias_kernel(const float* __restrict__ acc, const float* __restrict__ bias,
                                 float* __restrict__ xout, int total) {
  int i = blockIdx.x * blockDim.x + threadIdx.x;
  if (i >= total) return;
  int c = i & (HDIM - 1);
  xout[i] = fmaxf(acc[i] + bias[c], 0.f);
}

// out[i,0:2] = h2[i,:] @ W3 + b3
__global__ __launch_bounds__(256) void head3_kernel(
    const float* __restrict__ h2, const float* __restrict__ W3, const float* __restrict__ b3,
    float* __restrict__ out, int M, int K) {
  int i = blockIdx.x * 4 + (threadIdx.x >> 6);
  int lane = threadIdx.x & 63;
  if (i >= M) return;
  float s0 = 0.f, s1 = 0.f;
  for (int k = lane; k < K; k += 64) {
    float h = h2[(size_t)i * K + k];
    s0 += h * W3[k * 2 + 0];
    s1 += h * W3[k * 2 + 1];
  }
#pragma unroll
  for (int off = 32; off; off >>= 1) {
    s0 += __shfl_down(s0, off);
    s1 += __shfl_down(s1, off);
  }
  if (lane == 0) {
    out[(size_t)i * 2 + 0] = s0 + b3[0];
    out[(size_t)i * 2 + 1] = s1 + b3[1];
  }
}

// ---------------------------------------------------------------- host side
static inline int cdiv(int a, int b) { return (a + b - 1) / b; }

struct GatBufs {
  float *Hsrc, *Hdst, *als, *ald, *Mg, *den, *ebuf, *out;
};

static void build_sorted(hipStream_t stream,
                         const int* src, const int* dst, int E, int nloops, int Nd,
                         int* offs, int* binsum, int* base, int2* sd) {
  size_t lds = (size_t)Nd * sizeof(int);
  hist_kernel<<<NB, 256, lds, stream>>>(src, dst, E, nloops, Nd, offs);
  scan_bins_kernel<<<cdiv(Nd, 4), 256, 0, stream>>>(offs, binsum, Nd);
  scan_base_kernel<<<1, 256, 0, stream>>>(binsum, base, Nd);
  scatter_kernel<<<NB, 256, lds, stream>>>(src, dst, E, nloops, Nd, offs, base, sd);
}

static void run_gat(hipStream_t stream,
                    const float* Xsrc, int Ns, const float* Xdst, int Nd,
                    const float* W, const float* asrc, const float* adst, const float* bias,
                    const int2* sd, int tot,
                    const GatBufs& b, float* xout, int act /*0=l2norm,1=relu*/) {
  {
    dim3 g(cdiv(HDIM, TBN), cdiv(Ns, TBM));
    mfma_gemm<0, 0><<<g, 256, 0, stream>>>(Xsrc, nullptr, nullptr, nullptr, nullptr, nullptr, 0,
                                           W, nullptr, b.Hsrc, Ns, HDIM, HDIM);
  }
  const float* Hd = b.Hsrc;
  if (Xdst != Xsrc) {
    dim3 g(cdiv(HDIM, TBN), cdiv(Nd, TBM));
    mfma_gemm<0, 0><<<g, 256, 0, stream>>>(Xdst, nullptr, nullptr, nullptr, nullptr, nullptr, 0,
                                           W, nullptr, b.Hdst, Nd, HDIM, HDIM);
    Hd = b.Hdst;
  }
  rowdot_kernel<<<Ns, 64, 0, stream>>>(b.Hsrc, asrc, b.als, Ns);
  rowdot_kernel<<<Nd, 64, 0, stream>>>(Hd, adst, b.ald, Nd);
  fillf_kernel<<<1, 64, 0, stream>>>(b.Mg, -1e30f, 1);
  fillf_kernel<<<cdiv(Nd, 256), 256, 0, stream>>>(b.den, 0.f, Nd);
  fillf_kernel<<<cdiv(Nd * HDIM, 256), 256, 0, stream>>>(b.out, 0.f, Nd * HDIM);
  edge_pass1_kernel<<<cdiv(tot, 256), 256, 0, stream>>>(sd, tot, b.als, b.ald, b.ebuf, b.Mg);
  {
    int nb = cdiv(tot, 256); if (nb > 512) nb = 512;
    size_t lds = (size_t)Nd * sizeof(float);
    edge_pass2_kernel<<<nb, 256, lds, stream>>>(sd, tot, Nd, b.Mg, b.ebuf, b.den);
  }
  edge_aggregate_csr<<<cdiv(cdiv(tot, CS), 4), 256, 0, stream>>>(sd, tot, b.ebuf, b.den, b.Hsrc, b.out);
  if (act == 0)
    l2norm_bias_kernel<<<Nd, 64, 0, stream>>>(b.out, bias, xout, Nd);
  else
    relu_bias_kernel<<<cdiv(Nd * HDIM, 256), 256, 0, stream>>>(b.out, bias, xout, Nd * HDIM);
}

extern "C" void kernel_launch(void* const* d_in, const int* in_sizes, int n_in,
                              void* d_out, int out_size, void* d_ws, size_t ws_size,
                              hipStream_t stream) {
  const float* drug_emb = (const float*)d_in[0];
  const float* prot_emb = (const float*)d_in[1];
  const float* cell_emb = (const float*)d_in[2];
  const float* W_pp = (const float*)d_in[3];
  const float* as_pp = (const float*)d_in[4];
  const float* ad_pp = (const float*)d_in[5];
  const float* b_pp = (const float*)d_in[6];
  const float* W_dp = (const float*)d_in[7];
  const float* as_dp = (const float*)d_in[8];
  const float* ad_dp = (const float*)d_in[9];
  const float* b_dp = (const float*)d_in[10];
  const float* W_cp = (const float*)d_in[11];
  const float* as_cp = (const float*)d_in[12];
  const float* ad_cp = (const float*)d_in[13];
  const float* b_cp = (const float*)d_in[14];
  const float* W1 = (const float*)d_in[15];
  const float* b1 = (const float*)d_in[16];
  const float* W2 = (const float*)d_in[17];
  const float* b2 = (const float*)d_in[18];
  const float* W3 = (const float*)d_in[19];
  const float* b3 = (const float*)d_in[20];
  const int* edge_pp = (const int*)d_in[21];
  const int* edge_dp = (const int*)d_in[22];
  const int* edge_cp = (const int*)d_in[23];
  const int* drug1 = (const int*)d_in[24];
  const int* drug2 = (const int*)d_in[25];
  const int* cellb = (const int*)d_in[26];

  const int ND = in_sizes[0] / HDIM;
  const int NP = in_sizes[1] / HDIM;
  const int NC = in_sizes[2] / HDIM;
  const int L = in_sizes[3] / (HDIM * HDIM);
  const int E_pp = in_sizes[21] / 2;
  const int E_dp = in_sizes[22] / 2;
  const int E_cp = in_sizes[23] / 2;
  const int B = in_sizes[24];

  const int* src_pp = edge_pp;          const int* dst_pp = edge_pp + E_pp;
  const int* src_dp = edge_dp;          const int* dst_dp = edge_dp + E_dp;
  const int* src_cp = edge_cp;          const int* dst_cp = edge_cp + E_cp;
  const int tot_pp = E_pp + NP, tot_dp = E_dp, tot_cp = E_cp;

  float* ws = (float*)d_ws;
  size_t off = 0;
  auto alloc = [&](size_t n) { float* p = ws + off; off += (n + 3) & ~(size_t)3; return p; };
  int maxN = NP > ND ? NP : ND; if (NC > maxN) maxN = NC;
  int emax = tot_pp; if (tot_dp > emax) emax = tot_dp; if (tot_cp > emax) emax = tot_cp;

  float* xp  = alloc((size_t)NP * HDIM);
  float* xd  = alloc((size_t)ND * HDIM);
  float* xc  = alloc((size_t)NC * HDIM);
  float* xdn = alloc((size_t)ND * HDIM);
  float* xcn = alloc((size_t)NC * HDIM);
  size_t scratch0 = off;                       // reused: offs (builds) -> Hp.. (layers) -> h1/h2 (MLP)
  float* Hp  = alloc((size_t)NP * HDIM);
  float* Hd  = alloc((size_t)ND * HDIM);
  float* outb = alloc((size_t)NP * HDIM);
  float* als = alloc(maxN);
  float* ald = alloc(maxN);
  float* Mg  = alloc(4);
  float* den = alloc(maxN);
  float* ebuf = alloc(emax);
  // persistent sort outputs
  int* binsum = (int*)alloc(maxN);
  int* base   = (int*)alloc(maxN);
  int2* sd_pp = (int2*)alloc((size_t)tot_pp * 2);
  int2* sd_dp = (int2*)alloc((size_t)tot_dp * 2);
  int2* sd_cp = (int2*)alloc((size_t)tot_cp * 2);
  // offs aliases the scratch0 region (dead before Hp is first written)
  int* offs = (int*)(ws + scratch0);           // maxN*NB ints = 9.7 MB < region
  (void)ws_size; (void)n_in; (void)out_size;

  // ---- build dst-sorted edge lists (once; reused by both layers)
  build_sorted(stream, src_pp, dst_pp, E_pp, NP, NP, offs, binsum, base, sd_pp);
  build_sorted(stream, src_dp, dst_dp, E_dp, 0, ND, offs, binsum, base, sd_dp);
  build_sorted(stream, src_cp, dst_cp, E_cp, 0, NC, offs, binsum, base, sd_cp);

  GatBufs gb{Hp, Hd, als, ald, Mg, den, ebuf, outb};

  const float* cur_p = prot_emb;
  const float* cur_d = drug_emb;
  const float* cur_c = cell_emb;
  for (int l = 0; l < L; ++l) {
    const int WOFF = l * HDIM * HDIM, VOFF = l * HDIM;
    run_gat(stream, cur_p, NP, cur_p, NP, W_pp + WOFF, as_pp + VOFF, ad_pp + VOFF, b_pp + VOFF,
            sd_pp, tot_pp, gb, xp, /*l2norm*/0);
    run_gat(stream, xp, NP, cur_d, ND, W_dp + WOFF, as_dp + VOFF, ad_dp + VOFF, b_dp + VOFF,
            sd_dp, tot_dp, gb, xd, /*relu*/1);
    run_gat(stream, xp, NP, cur_c, NC, W_cp + WOFF, as_cp + VOFF, ad_cp + VOFF, b_cp + VOFF,
            sd_cp, tot_cp, gb, xc, /*relu*/1);
    cur_p = xp; cur_d = xd; cur_c = xc;
  }

  l2norm_bias_kernel<<<ND, 64, 0, stream>>>(xd, nullptr, xdn, ND);
  l2norm_bias_kernel<<<NC, 64, 0, stream>>>(xc, nullptr, xcn, NC);

  const int CH = 4096;
  float* h1 = ws + scratch0;
  float* h2 = h1 + (size_t)CH * 1536;
  float* outp = (float*)d_out;
  for (int c0 = 0; c0 < B; c0 += CH) {
    int M = (B - c0) < CH ? (B - c0) : CH;
    {
      dim3 g(cdiv(1536, TBN), cdiv(M, TBM));
      mfma_gemm<1, 1><<<g, 256, 0, stream>>>(nullptr, xdn, xcn, drug1, drug2, cellb, c0,
                                             W1, b1, h1, M, 1536, 768);
    }
    {
      dim3 g(cdiv(512, TBN), cdiv(M, TBM));
      mfma_gemm<1, 0><<<g, 256, 0, stream>>>(h1, nullptr, nullptr, nullptr, nullptr, nullptr, 0,
                                             W2, b2, h2, M, 512, 1536);
    }
    head3_kernel<<<cdiv(M, 4), 256, 0, stream>>>(h2, W3, b3, outp + (size_t)c0 * 2, M, 512);
  }
}

// Round 6
// 1574.220 us; speedup vs baseline: 3.2237x; 1.2732x over previous
//
#include <hip/hip_runtime.h>
#include <hip/hip_bf16.h>

#define HDIM 256
#define NEG_SLOPE 0.2f
#define NB 128          // blocks for hist/scatter
#define CS 128          // sorted-edge positions per wave in aggregate

typedef __attribute__((ext_vector_type(8))) short bf16x8;
typedef __attribute__((ext_vector_type(4))) float f32x4;

// split-bf16 "plane" element: uint = hi | (lo<<16), x ~= bf16(hi) + bf16(lo)
__device__ inline uint f2pl(float x) {
  __hip_bfloat16 h = __float2bfloat16(x);
  ushort hi = *(ushort*)&h;
  float r = x - __bfloat162float(h);
  __hip_bfloat16 l = __float2bfloat16(r);
  ushort lo = *(ushort*)&l;
  return (uint)hi | ((uint)lo << 16);
}
__device__ inline float pl2f(uint p) {
  ushort hi = (ushort)(p & 0xffff), lo = (ushort)(p >> 16);
  return __bfloat162float(*(__hip_bfloat16*)&hi) + __bfloat162float(*(__hip_bfloat16*)&lo);
}

// ---------------------------------------------------------------- utilities
__global__ void fillf_kernel(float* __restrict__ p, float v, int n) {
  int i = blockIdx.x * blockDim.x + threadIdx.x;
  if (i < n) p[i] = v;
}

// W[K][N] fp32 -> WT[N][K] planes
__global__ void wconv_kernel(const float* __restrict__ W, uint* __restrict__ WT,
                             int K, int N) {
  int i = blockIdx.x * 256 + threadIdx.x;
  if (i >= K * N) return;
  int k = i / N, n = i - k * N;
  WT[(size_t)n * K + k] = f2pl(W[i]);
}

// ---------------------------------------------------------------- MFMA GEMM
// C[M,N] = act(A@B + bias). B pre-transposed planes [N][K].
// AMODE: 0 = A planes [M][K]; 1 = A fp32 [M][K] (cvt in kernel); 2 = gathered planes
// OUTPL: 0 = fp32 C; 1 = plane C.  ACT: 1 = relu.
// 128x64 tile, BK=32, 256 threads (4 waves, each 64x32).
#define TBM 128
#define TBN 64
#define TBK 32
#define PITCH 40   // ushorts per LDS row (80B, 16B-aligned)

template <int AMODE, int OUTPL, int ACT>
__global__ __launch_bounds__(256) void mfma_gemm(
    const void* __restrict__ Av,
    const uint* __restrict__ xdn_pl, const uint* __restrict__ xcn_pl,
    const int* __restrict__ g1, const int* __restrict__ g2, const int* __restrict__ g3,
    int row0,
    const uint* __restrict__ BT, const float* __restrict__ bias,
    void* __restrict__ Cv, int M, int N, int K) {
  __shared__ ushort Ah[TBM][PITCH];
  __shared__ ushort Al[TBM][PITCH];
  __shared__ ushort Bh[TBN][PITCH];
  __shared__ ushort Bl[TBN][PITCH];

  const int tid = threadIdx.x;
  const int lane = tid & 63;
  const int wid = tid >> 6;
  const int wm = wid & 1, wn = wid >> 1;
  const int l16 = lane & 15;
  const int quad = lane >> 4;
  const int m0 = blockIdx.y * TBM;
  const int n0 = blockIdx.x * TBN;

  const int am = tid >> 1;            // 0..127 (A row)
  const int ah = (tid & 1) * 16;      // A k-el offset
  const int bn = tid >> 2;            // 0..63 (B row)
  const int bq = (tid & 3) * 8;       // B k-el offset

  f32x4 acc[4][2];
#pragma unroll
  for (int i = 0; i < 4; ++i)
#pragma unroll
    for (int j = 0; j < 2; ++j) acc[i][j] = (f32x4){0.f, 0.f, 0.f, 0.f};

  for (int k0 = 0; k0 < K; k0 += TBK) {
    __syncthreads();
    // ---- stage A (128 x 32)
    {
      int gm = m0 + am;
      if (AMODE == 1) {
        const float* A = (const float*)Av;
        const float* ap = (gm < M) ? A + (size_t)gm * K + k0 + ah : nullptr;
#pragma unroll
        for (int u = 0; u < 4; ++u) {
          float4 v = ap ? *(const float4*)(ap + u * 4) : make_float4(0.f, 0.f, 0.f, 0.f);
          uint p0 = f2pl(v.x), p1 = f2pl(v.y), p2 = f2pl(v.z), p3 = f2pl(v.w);
          ushort4 h = {(ushort)(p0 & 0xffff), (ushort)(p1 & 0xffff), (ushort)(p2 & 0xffff), (ushort)(p3 & 0xffff)};
          ushort4 l = {(ushort)(p0 >> 16), (ushort)(p1 >> 16), (ushort)(p2 >> 16), (ushort)(p3 >> 16)};
          *(ushort4*)&Ah[am][ah + u * 4] = h;
          *(ushort4*)&Al[am][ah + u * 4] = l;
        }
      } else {
        const uint* ap = nullptr;
        if (gm < M) {
          if (AMODE == 2) {
            int bi = row0 + gm;
            int seg = k0 >> 8;             // BK=32 tile never crosses a 256 boundary
            int idx = (seg == 0) ? g1[bi] : (seg == 1 ? g2[bi] : g3[bi]);
            ap = ((seg == 2) ? xcn_pl : xdn_pl) + (size_t)idx * HDIM + (k0 & 255) + ah;
          } else {
            ap = (const uint*)Av + (size_t)gm * K + k0 + ah;
          }
        }
#pragma unroll
        for (int u = 0; u < 4; ++u) {
          uint4 v = ap ? *(const uint4*)(ap + u * 4) : make_uint4(0, 0, 0, 0);
          ushort4 h = {(ushort)(v.x & 0xffff), (ushort)(v.y & 0xffff), (ushort)(v.z & 0xffff), (ushort)(v.w & 0xffff)};
          ushort4 l = {(ushort)(v.x >> 16), (ushort)(v.y >> 16), (ushort)(v.z >> 16), (ushort)(v.w >> 16)};
          *(ushort4*)&Ah[am][ah + u * 4] = h;
          *(ushort4*)&Al[am][ah + u * 4] = l;
        }
      }
    }
    // ---- stage B (64 x 32) from BT[n][k]
    {
      const uint* bp = BT + (size_t)(n0 + bn) * K + k0 + bq;
#pragma unroll
      for (int u = 0; u < 2; ++u) {
        uint4 v = *(const uint4*)(bp + u * 4);
        ushort4 h = {(ushort)(v.x & 0xffff), (ushort)(v.y & 0xffff), (ushort)(v.z & 0xffff), (ushort)(v.w & 0xffff)};
        ushort4 l = {(ushort)(v.x >> 16), (ushort)(v.y >> 16), (ushort)(v.z >> 16), (ushort)(v.w >> 16)};
        *(ushort4*)&Bh[bn][bq + u * 4] = h;
        *(ushort4*)&Bl[bn][bq + u * 4] = l;
      }
    }
    __syncthreads();

    bf16x8 ahf[4], alf[4], bhf[2], blf[2];
#pragma unroll
    for (int t = 0; t < 4; ++t) {
      int r = wm * 64 + t * 16 + l16;
      ahf[t] = *(const bf16x8*)&Ah[r][quad * 8];
      alf[t] = *(const bf16x8*)&Al[r][quad * 8];
    }
#pragma unroll
    for (int t = 0; t < 2; ++t) {
      int r = wn * 32 + t * 16 + l16;
      bhf[t] = *(const bf16x8*)&Bh[r][quad * 8];
      blf[t] = *(const bf16x8*)&Bl[r][quad * 8];
    }
#pragma unroll
    for (int tm = 0; tm < 4; ++tm)
#pragma unroll
      for (int tn = 0; tn < 2; ++tn) {
        acc[tm][tn] = __builtin_amdgcn_mfma_f32_16x16x32_bf16(ahf[tm], bhf[tn], acc[tm][tn], 0, 0, 0);
        acc[tm][tn] = __builtin_amdgcn_mfma_f32_16x16x32_bf16(ahf[tm], blf[tn], acc[tm][tn], 0, 0, 0);
        acc[tm][tn] = __builtin_amdgcn_mfma_f32_16x16x32_bf16(alf[tm], bhf[tn], acc[tm][tn], 0, 0, 0);
      }
  }

  // ---- epilogue: C/D layout col=lane&15, row=quad*4+reg
#pragma unroll
  for (int tn = 0; tn < 2; ++tn) {
    int col = n0 + wn * 32 + tn * 16 + l16;
    float bv = bias ? bias[col] : 0.f;
#pragma unroll
    for (int tm = 0; tm < 4; ++tm) {
#pragma unroll
      for (int r = 0; r < 4; ++r) {
        int row = m0 + wm * 64 + tm * 16 + quad * 4 + r;
        if (row >= M) continue;
        float v = acc[tm][tn][r] + bv;
        if (ACT == 1) v = fmaxf(v, 0.f);
        if (OUTPL) ((uint*)Cv)[(size_t)row * N + col] = f2pl(v);
        else       ((float*)Cv)[(size_t)row * N + col] = v;
      }
    }
  }
}

static inline int cdiv(int a, int b) { return (a + b - 1) / b; }

static void launch_gemm(hipStream_t s, int amode, int outpl_act,
                        const void* A, const uint* xdn, const uint* xcn,
                        const int* g1, const int* g2, const int* g3, int row0,
                        const uint* BT, const float* bias, void* C,
                        int M, int N, int K) {
  dim3 g(N / TBN, cdiv(M, TBM));
  if (amode == 2)       // gather -> planes+relu (MLP1)
    mfma_gemm<2, 1, 1><<<g, 256, 0, s>>>(A, xdn, xcn, g1, g2, g3, row0, BT, bias, C, M, N, K);
  else if (amode == 1)  // fp32 A -> fp32 C (layer-0 graph GEMMs)
    mfma_gemm<1, 0, 0><<<g, 256, 0, s>>>(A, xdn, xcn, g1, g2, g3, row0, BT, bias, C, M, N, K);
  else if (outpl_act)   // planes A -> fp32 C + relu (MLP2)
    mfma_gemm<0, 0, 1><<<g, 256, 0, s>>>(A, xdn, xcn, g1, g2, g3, row0, BT, bias, C, M, N, K);
  else                  // planes A -> fp32 C (graph GEMMs)
    mfma_gemm<0, 0, 0><<<g, 256, 0, s>>>(A, xdn, xcn, g1, g2, g3, row0, BT, bias, C, M, N, K);
}

// ---------------------------------------------------------------- row dot (4 rows/block)
__global__ __launch_bounds__(256) void rowdot_kernel(
    const float* __restrict__ H, const float* __restrict__ a,
    float* __restrict__ out, int n) {
  int row = blockIdx.x * 4 + (threadIdx.x >> 6);
  if (row >= n) return;
  int lane = threadIdx.x & 63;
  const float* h = H + (size_t)row * HDIM;
  float s = 0.f;
#pragma unroll
  for (int u = 0; u < 4; ++u) {
    int c = lane + u * 64;
    s += h[c] * a[c];
  }
#pragma unroll
  for (int off = 32; off; off >>= 1) s += __shfl_down(s, off);
  if (lane == 0) out[row] = s;
}

// ---------------------------------------------------------------- counting sort by dst
__global__ __launch_bounds__(256) void hist_kernel(
    const int* __restrict__ src, const int* __restrict__ dst, int E, int nloops,
    int Nd, int* __restrict__ offs) {
  extern __shared__ int bins[];
  int tot = E + nloops;
  int chunk = (tot + NB - 1) / NB;
  int b = blockIdx.x;
  int s0 = b * chunk, s1 = min(s0 + chunk, tot);
  for (int i = threadIdx.x; i < Nd; i += 256) bins[i] = 0;
  __syncthreads();
  for (int i = s0 + threadIdx.x; i < s1; i += 256) {
    int d = (i < E) ? dst[i] : (i - E);
    atomicAdd(&bins[d], 1);
  }
  __syncthreads();
  for (int i = threadIdx.x; i < Nd; i += 256) offs[(size_t)i * NB + b] = bins[i];
}

__global__ __launch_bounds__(256) void scan_bins_kernel(
    int* __restrict__ offs, int* __restrict__ binsum, int Nd) {
  int d = blockIdx.x * 4 + (threadIdx.x >> 6);
  if (d >= Nd) return;
  int lane = threadIdx.x & 63;
  int* p = offs + (size_t)d * NB;
  int v0 = p[2 * lane], v1 = p[2 * lane + 1];
  int s = v0 + v1;
  int t = s;
#pragma unroll
  for (int o = 1; o < 64; o <<= 1) { int u = __shfl_up(t, o); if (lane >= o) t += u; }
  int excl = t - s;
  p[2 * lane] = excl;
  p[2 * lane + 1] = excl + v0;
  if (lane == 63) binsum[d] = t;
}

__global__ __launch_bounds__(256) void scan_base_kernel(
    const int* __restrict__ binsum, int* __restrict__ base, int Nd) {
  __shared__ int wsum[4];
  __shared__ int carry;
  if (threadIdx.x == 0) carry = 0;
  __syncthreads();
  int lane = threadIdx.x & 63, w = threadIdx.x >> 6;
  for (int t0 = 0; t0 < Nd; t0 += 256) {
    int i = t0 + threadIdx.x;
    int v = (i < Nd) ? binsum[i] : 0;
    int t = v;
#pragma unroll
    for (int o = 1; o < 64; o <<= 1) { int u = __shfl_up(t, o); if (lane >= o) t += u; }
    if (lane == 63) wsum[w] = t;
    __syncthreads();
    int add = carry;
    for (int k = 0; k < w; ++k) add += wsum[k];
    if (i < Nd) base[i] = t - v + add;
    __syncthreads();
    if (threadIdx.x == 0) carry += wsum[0] + wsum[1] + wsum[2] + wsum[3];
    __syncthreads();
  }
}

// scatter to sorted position; packed u32 = src | dst<<16 (ids < 2^15)
__global__ __launch_bounds__(256) void scatter_kernel(
    const int* __restrict__ src, const int* __restrict__ dst, int E, int nloops,
    int Nd, const int* __restrict__ offs, const int* __restrict__ base,
    uint* __restrict__ sd) {
  extern __shared__ int bins[];
  int tot = E + nloops;
  int chunk = (tot + NB - 1) / NB;
  int b = blockIdx.x;
  int s0 = b * chunk, s1 = min(s0 + chunk, tot);
  for (int i = threadIdx.x; i < Nd; i += 256) bins[i] = 0;
  __syncthreads();
  for (int i = s0 + threadIdx.x; i < s1; i += 256) {
    int s_, d_;
    if (i < E) { s_ = src[i]; d_ = dst[i]; }
    else       { s_ = d_ = i - E; }
    int local = atomicAdd(&bins[d_], 1);
    int pos = base[d_] + offs[(size_t)d_ * NB + b] + local;
    sd[pos] = (uint)s_ | ((uint)d_ << 16);
  }
}

// ---------------------------------------------------------------- edge passes
__device__ inline void atomicMaxF(float* addr, float val) {
  if (val >= 0.f)
    atomicMax((int*)addr, __float_as_int(val));
  else
    atomicMin((unsigned int*)addr, __float_as_uint(val));
}

__global__ __launch_bounds__(256) void edge_pass1_kernel(
    const uint* __restrict__ sd, int tot,
    const float* __restrict__ als, const float* __restrict__ ald,
    float* __restrict__ ebuf, float* __restrict__ Mg) {
  int i = blockIdx.x * 256 + threadIdx.x;
  float v = -1e30f;
  if (i < tot) {
    uint p = sd[i];
    float x = als[p & 0xffff] + ald[p >> 16];
    x = (x > 0.f) ? x : NEG_SLOPE * x;
    ebuf[i] = x;
    v = x;
  }
#pragma unroll
  for (int off = 32; off; off >>= 1) v = fmaxf(v, __shfl_down(v, off));
  __shared__ float wmax[4];
  if ((threadIdx.x & 63) == 0) wmax[threadIdx.x >> 6] = v;
  __syncthreads();
  if (threadIdx.x == 0) {
    float b = fmaxf(fmaxf(wmax[0], wmax[1]), fmaxf(wmax[2], wmax[3]));
    atomicMaxF(Mg, b);
  }
}

__global__ __launch_bounds__(256) void edge_pass2_kernel(
    const uint* __restrict__ sd, int tot, int Nd,
    const float* __restrict__ Mg,
    float* __restrict__ ebuf, float* __restrict__ denom) {
  extern __shared__ float sden[];
  for (int i = threadIdx.x; i < Nd; i += 256) sden[i] = 0.f;
  __syncthreads();
  const float mg = Mg[0];
  for (int i = blockIdx.x * 256 + threadIdx.x; i < tot; i += gridDim.x * 256) {
    float ex = __expf(ebuf[i] - mg);
    ebuf[i] = ex;
    atomicAdd(&sden[sd[i] >> 16], ex);
  }
  __syncthreads();
  for (int i = threadIdx.x; i < Nd; i += 256) {
    float v = sden[i];
    if (v != 0.f) atomicAdd(&denom[i], v);
  }
}

// segmented reduction over dst-sorted edges; one flush per segment
__global__ __launch_bounds__(256) void edge_aggregate_csr(
    const uint* __restrict__ sd, int tot,
    const float* __restrict__ ebuf, const float* __restrict__ denom,
    const float* __restrict__ H, float* __restrict__ out) {
  int w = blockIdx.x * 4 + (threadIdx.x >> 6);
  int lane = threadIdx.x & 63;
  int s0 = w * CS;
  if (s0 >= tot) return;
  int s1 = min(s0 + CS, tot);
  float4 acc = make_float4(0.f, 0.f, 0.f, 0.f);
  int cur = sd[s0] >> 16;
  for (int i = s0; i < s1; ++i) {
    uint p = sd[i];
    int d_ = p >> 16;
    if (d_ != cur) {
      float* o = out + (size_t)cur * HDIM + lane * 4;
      atomicAdd(o + 0, acc.x); atomicAdd(o + 1, acc.y);
      atomicAdd(o + 2, acc.z); atomicAdd(o + 3, acc.w);
      acc = make_float4(0.f, 0.f, 0.f, 0.f);
      cur = d_;
    }
    float coef = ebuf[i] / (denom[d_] + 1e-16f);
    float4 h = *(const float4*)(H + (size_t)(p & 0xffff) * HDIM + lane * 4);
    acc.x += coef * h.x; acc.y += coef * h.y;
    acc.z += coef * h.z; acc.w += coef * h.w;
  }
  float* o = out + (size_t)cur * HDIM + lane * 4;
  atomicAdd(o + 0, acc.x); atomicAdd(o + 1, acc.y);
  atomicAdd(o + 2, acc.z); atomicAdd(o + 3, acc.w);
}

// ---------------------------------------------------------------- finalize (write planes)
template <int IN_PL>
__global__ __launch_bounds__(256) void l2norm_pl_kernel(
    const void* __restrict__ in, const float* __restrict__ bias,
    uint* __restrict__ out_pl, int n) {
  int row = blockIdx.x * 4 + (threadIdx.x >> 6);
  if (row >= n) return;
  int lane = threadIdx.x & 63;
  float v[4];
  float ss = 0.f;
#pragma unroll
  for (int u = 0; u < 4; ++u) {
    int c = lane + u * 64;
    float t = IN_PL ? pl2f(((const uint*)in)[(size_t)row * HDIM + c])
                    : ((const float*)in)[(size_t)row * HDIM + c];
    if (bias) t += bias[c];
    v[u] = t;
    ss += t * t;
  }
#pragma unroll
  for (int off = 32; off; off >>= 1) ss += __shfl_xor(ss, off);
  float sc = 1.0f / fmaxf(sqrtf(ss), 1e-12f);
#pragma unroll
  for (int u = 0; u < 4; ++u) {
    int c = lane + u * 64;
    out_pl[(size_t)row * HDIM + c] = f2pl(v[u] * sc);
  }
}

__global__ void relu_pl_kernel(const float* __restrict__ acc, const float* __restrict__ bias,
                               uint* __restrict__ out_pl, int total) {
  int i = blockIdx.x * blockDim.x + threadIdx.x;
  if (i >= total) return;
  int c = i & (HDIM - 1);
  out_pl[i] = f2pl(fmaxf(acc[i] + bias[c], 0.f));
}

// out[i,0:2] = h2[i,:] @ W3 + b3
__global__ __launch_bounds__(256) void head3_kernel(
    const float* __restrict__ h2, const float* __restrict__ W3, const float* __restrict__ b3,
    float* __restrict__ out, int M, int K) {
  int i = blockIdx.x * 4 + (threadIdx.x >> 6);
  int lane = threadIdx.x & 63;
  if (i >= M) return;
  float s0 = 0.f, s1 = 0.f;
  for (int k = lane; k < K; k += 64) {
    float h = h2[(size_t)i * K + k];
    s0 += h * W3[k * 2 + 0];
    s1 += h * W3[k * 2 + 1];
  }
#pragma unroll
  for (int off = 32; off; off >>= 1) {
    s0 += __shfl_down(s0, off);
    s1 += __shfl_down(s1, off);
  }
  if (lane == 0) {
    out[(size_t)i * 2 + 0] = s0 + b3[0];
    out[(size_t)i * 2 + 1] = s1 + b3[1];
  }
}

// ---------------------------------------------------------------- host side
struct GatBufs {
  float *Hsrc, *Hdst, *als, *ald, *Mg, *den, *ebuf, *out;
};

static void build_sorted(hipStream_t stream,
                         const int* src, const int* dst, int E, int nloops, int Nd,
                         int* offs, int* binsum, int* base, uint* sd) {
  size_t lds = (size_t)Nd * sizeof(int);
  hist_kernel<<<NB, 256, lds, stream>>>(src, dst, E, nloops, Nd, offs);
  scan_bins_kernel<<<cdiv(Nd, 4), 256, 0, stream>>>(offs, binsum, Nd);
  scan_base_kernel<<<1, 256, 0, stream>>>(binsum, base, Nd);
  scatter_kernel<<<NB, 256, lds, stream>>>(src, dst, E, nloops, Nd, offs, base, sd);
}

static void run_gat(hipStream_t stream,
                    const void* Xsrc, int src_mode, int Ns,
                    const void* Xdst, int dst_mode, int Nd, bool same,
                    const uint* WT, const float* asrc, const float* adst, const float* bias,
                    const uint* sd, int tot,
                    const GatBufs& b, uint* xout_pl, int act /*0=l2norm,1=relu*/) {
  launch_gemm(stream, src_mode, 0, Xsrc, nullptr, nullptr, nullptr, nullptr, nullptr, 0,
              WT, nullptr, b.Hsrc, Ns, HDIM, HDIM);
  const float* Hd = b.Hsrc;
  if (!same) {
    launch_gemm(stream, dst_mode, 0, Xdst, nullptr, nullptr, nullptr, nullptr, nullptr, 0,
                WT, nullptr, b.Hdst, Nd, HDIM, HDIM);
    Hd = b.Hdst;
  }
  rowdot_kernel<<<cdiv(Ns, 4), 256, 0, stream>>>(b.Hsrc, asrc, b.als, Ns);
  rowdot_kernel<<<cdiv(Nd, 4), 256, 0, stream>>>(Hd, adst, b.ald, Nd);
  fillf_kernel<<<1, 64, 0, stream>>>(b.Mg, -1e30f, 1);
  fillf_kernel<<<cdiv(Nd, 256), 256, 0, stream>>>(b.den, 0.f, Nd);
  fillf_kernel<<<cdiv(Nd * HDIM, 256), 256, 0, stream>>>(b.out, 0.f, Nd * HDIM);
  edge_pass1_kernel<<<cdiv(tot, 256), 256, 0, stream>>>(sd, tot, b.als, b.ald, b.ebuf, b.Mg);
  {
    int nb = cdiv(tot, 256); if (nb > 512) nb = 512;
    size_t lds = (size_t)Nd * sizeof(float);
    edge_pass2_kernel<<<nb, 256, lds, stream>>>(sd, tot, Nd, b.Mg, b.ebuf, b.den);
  }
  edge_aggregate_csr<<<cdiv(cdiv(tot, CS), 4), 256, 0, stream>>>(sd, tot, b.ebuf, b.den, b.Hsrc, b.out);
  if (act == 0)
    l2norm_pl_kernel<0><<<cdiv(Nd, 4), 256, 0, stream>>>(b.out, bias, xout_pl, Nd);
  else
    relu_pl_kernel<<<cdiv(Nd * HDIM, 256), 256, 0, stream>>>(b.out, bias, xout_pl, Nd * HDIM);
}

extern "C" void kernel_launch(void* const* d_in, const int* in_sizes, int n_in,
                              void* d_out, int out_size, void* d_ws, size_t ws_size,
                              hipStream_t stream) {
  const float* drug_emb = (const float*)d_in[0];
  const float* prot_emb = (const float*)d_in[1];
  const float* cell_emb = (const float*)d_in[2];
  const float* W_pp = (const float*)d_in[3];
  const float* as_pp = (const float*)d_in[4];
  const float* ad_pp = (const float*)d_in[5];
  const float* b_pp = (const float*)d_in[6];
  const float* W_dp = (const float*)d_in[7];
  const float* as_dp = (const float*)d_in[8];
  const float* ad_dp = (const float*)d_in[9];
  const float* b_dp = (const float*)d_in[10];
  const float* W_cp = (const float*)d_in[11];
  const float* as_cp = (const float*)d_in[12];
  const float* ad_cp = (const float*)d_in[13];
  const float* b_cp = (const float*)d_in[14];
  const float* W1 = (const float*)d_in[15];
  const float* b1 = (const float*)d_in[16];
  const float* W2 = (const float*)d_in[17];
  const float* b2 = (const float*)d_in[18];
  const float* W3 = (const float*)d_in[19];
  const float* b3 = (const float*)d_in[20];
  const int* edge_pp = (const int*)d_in[21];
  const int* edge_dp = (const int*)d_in[22];
  const int* edge_cp = (const int*)d_in[23];
  const int* drug1 = (const int*)d_in[24];
  const int* drug2 = (const int*)d_in[25];
  const int* cellb = (const int*)d_in[26];

  const int ND = in_sizes[0] / HDIM;   // 2000
  const int NP = in_sizes[1] / HDIM;   // 19000
  const int NC = in_sizes[2] / HDIM;   // 100
  const int L = in_sizes[3] / (HDIM * HDIM);  // 2
  const int E_pp = in_sizes[21] / 2;
  const int E_dp = in_sizes[22] / 2;
  const int E_cp = in_sizes[23] / 2;
  const int B = in_sizes[24];          // 8192

  const int* src_pp = edge_pp;          const int* dst_pp = edge_pp + E_pp;
  const int* src_dp = edge_dp;          const int* dst_dp = edge_dp + E_dp;
  const int* src_cp = edge_cp;          const int* dst_cp = edge_cp + E_cp;
  const int tot_pp = E_pp + NP, tot_dp = E_dp, tot_cp = E_cp;

  // ---------------- workspace layout (~72 MB peak)
  float* ws = (float*)d_ws;
  size_t off = 0;
  auto alloc = [&](size_t n) { float* p = ws + off; off += (n + 3) & ~(size_t)3; return p; };
  int maxN = NP > ND ? NP : ND; if (NC > maxN) maxN = NC;
  int emax = tot_pp; if (tot_dp > emax) emax = tot_dp; if (tot_cp > emax) emax = tot_cp;

  // persistent
  uint* xp_pl  = (uint*)alloc((size_t)NP * HDIM);
  uint* xd_pl  = (uint*)alloc((size_t)ND * HDIM);
  uint* xc_pl  = (uint*)alloc((size_t)NC * HDIM);
  uint* xdn_pl = (uint*)alloc((size_t)ND * HDIM);
  uint* xcn_pl = (uint*)alloc((size_t)NC * HDIM);
  uint* WTpp = (uint*)alloc((size_t)L * HDIM * HDIM);
  uint* WTdp = (uint*)alloc((size_t)L * HDIM * HDIM);
  uint* WTcp = (uint*)alloc((size_t)L * HDIM * HDIM);
  float* Mg  = alloc(4);
  int* binsum = (int*)alloc(maxN);
  int* base   = (int*)alloc(maxN);
  uint* sd_pp = (uint*)alloc(tot_pp);
  uint* sd_dp = (uint*)alloc(tot_dp);
  uint* sd_cp = (uint*)alloc(tot_cp);
  // scratch region S (graph bufs; overlaid by offs during sort-build, by MLP after)
  size_t S0 = off;
  float* Hp   = alloc((size_t)NP * HDIM);
  float* Hd   = alloc((size_t)ND * HDIM);
  float* outb = alloc((size_t)NP * HDIM);
  float* als = alloc(maxN);
  float* ald = alloc(maxN);
  float* den = alloc(maxN);
  float* ebuf = alloc(emax);
  (void)ws_size; (void)n_in; (void)out_size;

  // ---- sort builds (offs overlays Hp slot; dead before first GEMM writes Hp)
  int* offs = (int*)(ws + S0);
  build_sorted(stream, src_pp, dst_pp, E_pp, NP, NP, offs, binsum, base, sd_pp);
  build_sorted(stream, src_dp, dst_dp, E_dp, 0, ND, offs, binsum, base, sd_dp);
  build_sorted(stream, src_cp, dst_cp, E_cp, 0, NC, offs, binsum, base, sd_cp);

  // ---- weight planes (transposed) for graph convs
  for (int l = 0; l < L; ++l) {
    int WOFF = l * HDIM * HDIM;
    wconv_kernel<<<cdiv(HDIM * HDIM, 256), 256, 0, stream>>>(W_pp + WOFF, WTpp + WOFF, HDIM, HDIM);
    wconv_kernel<<<cdiv(HDIM * HDIM, 256), 256, 0, stream>>>(W_dp + WOFF, WTdp + WOFF, HDIM, HDIM);
    wconv_kernel<<<cdiv(HDIM * HDIM, 256), 256, 0, stream>>>(W_cp + WOFF, WTcp + WOFF, HDIM, HDIM);
  }

  GatBufs gb{Hp, Hd, als, ald, Mg, den, ebuf, outb};

  for (int l = 0; l < L; ++l) {
    const int WOFF = l * HDIM * HDIM, VOFF = l * HDIM;
    // p-p conv (self loops), l2norm -> xp_pl
    run_gat(stream,
            l == 0 ? (const void*)prot_emb : (const void*)xp_pl, l == 0 ? 1 : 0, NP,
            nullptr, 0, NP, /*same=*/true,
            WTpp + WOFF, as_pp + VOFF, ad_pp + VOFF, b_pp + VOFF,
            sd_pp, tot_pp, gb, xp_pl, 0);
    // d-p conv: src = proteins (new xp_pl), dst = drugs; relu -> xd_pl
    run_gat(stream, xp_pl, 0, NP,
            l == 0 ? (const void*)drug_emb : (const void*)xd_pl, l == 0 ? 1 : 0, ND, false,
            WTdp + WOFF, as_dp + VOFF, ad_dp + VOFF, b_dp + VOFF,
            sd_dp, tot_dp, gb, xd_pl, 1);
    // c-p conv: src = proteins, dst = cells; relu -> xc_pl
    run_gat(stream, xp_pl, 0, NP,
            l == 0 ? (const void*)cell_emb : (const void*)xc_pl, l == 0 ? 1 : 0, NC, false,
            WTcp + WOFF, as_cp + VOFF, ad_cp + VOFF, b_cp + VOFF,
            sd_cp, tot_cp, gb, xc_pl, 1);
  }

  // ---------------- head
  l2norm_pl_kernel<1><<<cdiv(ND, 4), 256, 0, stream>>>(xd_pl, nullptr, xdn_pl, ND);
  l2norm_pl_kernel<1><<<cdiv(NC, 4), 256, 0, stream>>>(xc_pl, nullptr, xcn_pl, NC);

  // MLP weight planes + buffers overlay S (graph bufs now dead)
  uint* W1T = (uint*)(ws + S0);                       // [1536][768]
  uint* W2T = W1T + (size_t)768 * 1536;               // [512][1536]
  const int CH = 4096;
  uint* h1_pl = W2T + (size_t)1536 * 512;             // [CH][1536] planes
  float* h2 = (float*)(h1_pl + (size_t)CH * 1536);    // [CH][512] fp32
  wconv_kernel<<<cdiv(768 * 1536, 256), 256, 0, stream>>>(W1, W1T, 768, 1536);
  wconv_kernel<<<cdiv(1536 * 512, 256), 256, 0, stream>>>(W2, W2T, 1536, 512);

  float* outp = (float*)d_out;
  for (int c0 = 0; c0 < B; c0 += CH) {
    int M = (B - c0) < CH ? (B - c0) : CH;
    launch_gemm(stream, 2, 1, nullptr, xdn_pl, xcn_pl, drug1, drug2, cellb, c0,
                W1T, b1, h1_pl, M, 1536, 768);
    launch_gemm(stream, 0, 1, h1_pl, nullptr, nullptr, nullptr, nullptr, nullptr, 0,
                W2T, b2, h2, M, 512, 1536);
    head3_kernel<<<cdiv(M, 4), 256, 0, stream>>>(h2, W3, b3, outp + (size_t)c0 * 2, M, 512);
  }
}

// Round 7
// 1417.803 us; speedup vs baseline: 3.5794x; 1.1103x over previous
//
#include <hip/hip_runtime.h>
#include <hip/hip_bf16.h>

#define HDIM 256
#define NEG_SLOPE 0.2f
#define NB 128          // blocks for hist/scatter

typedef __attribute__((ext_vector_type(8))) short bf16x8;
typedef __attribute__((ext_vector_type(4))) float f32x4;

// split-bf16 "plane": uint = hi | (lo<<16), x ~= bf16(hi) + bf16(lo)
__device__ inline uint f2pl(float x) {
  __hip_bfloat16 h = __float2bfloat16(x);
  ushort hi = *(ushort*)&h;
  float r = x - __bfloat162float(h);
  __hip_bfloat16 l = __float2bfloat16(r);
  ushort lo = *(ushort*)&l;
  return (uint)hi | ((uint)lo << 16);
}
__device__ inline float pl2f(uint p) {
  ushort hi = (ushort)(p & 0xffff), lo = (ushort)(p >> 16);
  return __bfloat162float(*(__hip_bfloat16*)&hi) + __bfloat162float(*(__hip_bfloat16*)&lo);
}
__device__ inline ushort f2b(float x) {
  __hip_bfloat16 h = __float2bfloat16(x);
  return *(ushort*)&h;
}
__device__ inline float b2f(ushort u) {
  uint x = ((uint)u) << 16;
  return __int_as_float((int)x);
}

static inline int cdiv(int a, int b) { return (a + b - 1) / b; }

// ---------------------------------------------------------------- weight planes: W[K][N] -> WT[N][K]
__global__ void wconv_kernel(const float* __restrict__ W, uint* __restrict__ WT,
                             int K, int N) {
  int i = blockIdx.x * 256 + threadIdx.x;
  if (i >= K * N) return;
  int k = i / N, n = i - k * N;
  WT[(size_t)n * K + k] = f2pl(W[i]);
}

// ---------------------------------------------------------------- MFMA GEMM
// C = act(A@B + bias). B pre-transposed planes [N][K].
// AMODE: 0 planes A; 1 fp32 A; 2 gathered planes.
// OUTMODE: 0 fp32 C; 1 plane C; 2 fp32 C + bf16 copy Cb.
#define TBM 128
#define TBN 64
#define TBK 32
#define PITCH 40

template <int AMODE, int OUTMODE, int ACT>
__global__ __launch_bounds__(256) void mfma_gemm(
    const void* __restrict__ Av,
    const uint* __restrict__ xdn_pl, const uint* __restrict__ xcn_pl,
    const int* __restrict__ g1, const int* __restrict__ g2, const int* __restrict__ g3,
    int row0,
    const uint* __restrict__ BT, const float* __restrict__ bias,
    void* __restrict__ Cv, ushort* __restrict__ Cb, int M, int N, int K) {
  __shared__ ushort Ah[TBM][PITCH];
  __shared__ ushort Al[TBM][PITCH];
  __shared__ ushort Bh[TBN][PITCH];
  __shared__ ushort Bl[TBN][PITCH];

  const int tid = threadIdx.x;
  const int lane = tid & 63;
  const int wid = tid >> 6;
  const int wm = wid & 1, wn = wid >> 1;
  const int l16 = lane & 15;
  const int quad = lane >> 4;
  const int m0 = blockIdx.y * TBM;
  const int n0 = blockIdx.x * TBN;

  const int am = tid >> 1;
  const int ah = (tid & 1) * 16;
  const int bn = tid >> 2;
  const int bq = (tid & 3) * 8;

  f32x4 acc[4][2];
#pragma unroll
  for (int i = 0; i < 4; ++i)
#pragma unroll
    for (int j = 0; j < 2; ++j) acc[i][j] = (f32x4){0.f, 0.f, 0.f, 0.f};

  for (int k0 = 0; k0 < K; k0 += TBK) {
    __syncthreads();
    {
      int gm = m0 + am;
      if (AMODE == 1) {
        const float* A = (const float*)Av;
        const float* ap = (gm < M) ? A + (size_t)gm * K + k0 + ah : nullptr;
#pragma unroll
        for (int u = 0; u < 4; ++u) {
          float4 v = ap ? *(const float4*)(ap + u * 4) : make_float4(0.f, 0.f, 0.f, 0.f);
          uint p0 = f2pl(v.x), p1 = f2pl(v.y), p2 = f2pl(v.z), p3 = f2pl(v.w);
          ushort4 h = {(ushort)(p0 & 0xffff), (ushort)(p1 & 0xffff), (ushort)(p2 & 0xffff), (ushort)(p3 & 0xffff)};
          ushort4 l = {(ushort)(p0 >> 16), (ushort)(p1 >> 16), (ushort)(p2 >> 16), (ushort)(p3 >> 16)};
          *(ushort4*)&Ah[am][ah + u * 4] = h;
          *(ushort4*)&Al[am][ah + u * 4] = l;
        }
      } else {
        const uint* ap = nullptr;
        if (gm < M) {
          if (AMODE == 2) {
            int bi = row0 + gm;
            int seg = k0 >> 8;
            int idx = (seg == 0) ? g1[bi] : (seg == 1 ? g2[bi] : g3[bi]);
            ap = ((seg == 2) ? xcn_pl : xdn_pl) + (size_t)idx * HDIM + (k0 & 255) + ah;
          } else {
            ap = (const uint*)Av + (size_t)gm * K + k0 + ah;
          }
        }
#pragma unroll
        for (int u = 0; u < 4; ++u) {
          uint4 v = ap ? *(const uint4*)(ap + u * 4) : make_uint4(0, 0, 0, 0);
          ushort4 h = {(ushort)(v.x & 0xffff), (ushort)(v.y & 0xffff), (ushort)(v.z & 0xffff), (ushort)(v.w & 0xffff)};
          ushort4 l = {(ushort)(v.x >> 16), (ushort)(v.y >> 16), (ushort)(v.z >> 16), (ushort)(v.w >> 16)};
          *(ushort4*)&Ah[am][ah + u * 4] = h;
          *(ushort4*)&Al[am][ah + u * 4] = l;
        }
      }
    }
    {
      const uint* bp = BT + (size_t)(n0 + bn) * K + k0 + bq;
#pragma unroll
      for (int u = 0; u < 2; ++u) {
        uint4 v = *(const uint4*)(bp + u * 4);
        ushort4 h = {(ushort)(v.x & 0xffff), (ushort)(v.y & 0xffff), (ushort)(v.z & 0xffff), (ushort)(v.w & 0xffff)};
        ushort4 l = {(ushort)(v.x >> 16), (ushort)(v.y >> 16), (ushort)(v.z >> 16), (ushort)(v.w >> 16)};
        *(ushort4*)&Bh[bn][bq + u * 4] = h;
        *(ushort4*)&Bl[bn][bq + u * 4] = l;
      }
    }
    __syncthreads();

    bf16x8 ahf[4], alf[4], bhf[2], blf[2];
#pragma unroll
    for (int t = 0; t < 4; ++t) {
      int r = wm * 64 + t * 16 + l16;
      ahf[t] = *(const bf16x8*)&Ah[r][quad * 8];
      alf[t] = *(const bf16x8*)&Al[r][quad * 8];
    }
#pragma unroll
    for (int t = 0; t < 2; ++t) {
      int r = wn * 32 + t * 16 + l16;
      bhf[t] = *(const bf16x8*)&Bh[r][quad * 8];
      blf[t] = *(const bf16x8*)&Bl[r][quad * 8];
    }
#pragma unroll
    for (int tm = 0; tm < 4; ++tm)
#pragma unroll
      for (int tn = 0; tn < 2; ++tn) {
        acc[tm][tn] = __builtin_amdgcn_mfma_f32_16x16x32_bf16(ahf[tm], bhf[tn], acc[tm][tn], 0, 0, 0);
        acc[tm][tn] = __builtin_amdgcn_mfma_f32_16x16x32_bf16(ahf[tm], blf[tn], acc[tm][tn], 0, 0, 0);
        acc[tm][tn] = __builtin_amdgcn_mfma_f32_16x16x32_bf16(alf[tm], bhf[tn], acc[tm][tn], 0, 0, 0);
      }
  }

#pragma unroll
  for (int tn = 0; tn < 2; ++tn) {
    int col = n0 + wn * 32 + tn * 16 + l16;
    float bv = bias ? bias[col] : 0.f;
#pragma unroll
    for (int tm = 0; tm < 4; ++tm) {
#pragma unroll
      for (int r = 0; r < 4; ++r) {
        int row = m0 + wm * 64 + tm * 16 + quad * 4 + r;
        if (row >= M) continue;
        float v = acc[tm][tn][r] + bv;
        if (ACT == 1) v = fmaxf(v, 0.f);
        if (OUTMODE == 1) ((uint*)Cv)[(size_t)row * N + col] = f2pl(v);
        else {
          ((float*)Cv)[(size_t)row * N + col] = v;
          if (OUTMODE == 2) Cb[(size_t)row * N + col] = f2b(v);
        }
      }
    }
  }
}

static void launch_gemm(hipStream_t s, int amode, int outmode, int act,
                        const void* A, const uint* xdn, const uint* xcn,
                        const int* g1, const int* g2, const int* g3, int row0,
                        const uint* BT, const float* bias, void* C, ushort* Cb,
                        int M, int N, int K) {
  dim3 g(N / TBN, cdiv(M, TBM));
  if (amode == 2)
    mfma_gemm<2, 1, 1><<<g, 256, 0, s>>>(A, xdn, xcn, g1, g2, g3, row0, BT, bias, C, Cb, M, N, K);
  else if (amode == 1 && outmode == 2)
    mfma_gemm<1, 2, 0><<<g, 256, 0, s>>>(A, xdn, xcn, g1, g2, g3, row0, BT, bias, C, Cb, M, N, K);
  else if (amode == 1)
    mfma_gemm<1, 0, 0><<<g, 256, 0, s>>>(A, xdn, xcn, g1, g2, g3, row0, BT, bias, C, Cb, M, N, K);
  else if (outmode == 2)
    mfma_gemm<0, 2, 0><<<g, 256, 0, s>>>(A, xdn, xcn, g1, g2, g3, row0, BT, bias, C, Cb, M, N, K);
  else if (act == 1)
    mfma_gemm<0, 0, 1><<<g, 256, 0, s>>>(A, xdn, xcn, g1, g2, g3, row0, BT, bias, C, Cb, M, N, K);
  else
    mfma_gemm<0, 0, 0><<<g, 256, 0, s>>>(A, xdn, xcn, g1, g2, g3, row0, BT, bias, C, Cb, M, N, K);
}

// ---------------------------------------------------------------- row dots
__global__ __launch_bounds__(256) void rowdot_kernel(
    const float* __restrict__ H, const float* __restrict__ a,
    float* __restrict__ out, int n) {
  int row = blockIdx.x * 4 + (threadIdx.x >> 6);
  if (row >= n) return;
  int lane = threadIdx.x & 63;
  const float* h = H + (size_t)row * HDIM;
  float s = 0.f;
#pragma unroll
  for (int u = 0; u < 4; ++u) {
    int c = lane + u * 64;
    s += h[c] * a[c];
  }
#pragma unroll
  for (int off = 32; off; off >>= 1) s += __shfl_down(s, off);
  if (lane == 0) out[row] = s;
}

// two dots over the same H in one pass (pp conv)
__global__ __launch_bounds__(256) void rowdot2_kernel(
    const float* __restrict__ H, const float* __restrict__ a1, const float* __restrict__ a2,
    float* __restrict__ o1, float* __restrict__ o2, int n) {
  int row = blockIdx.x * 4 + (threadIdx.x >> 6);
  if (row >= n) return;
  int lane = threadIdx.x & 63;
  const float* h = H + (size_t)row * HDIM;
  float s1 = 0.f, s2 = 0.f;
#pragma unroll
  for (int u = 0; u < 4; ++u) {
    int c = lane + u * 64;
    float hv = h[c];
    s1 += hv * a1[c];
    s2 += hv * a2[c];
  }
#pragma unroll
  for (int off = 32; off; off >>= 1) {
    s1 += __shfl_down(s1, off);
    s2 += __shfl_down(s2, off);
  }
  if (lane == 0) { o1[row] = s1; o2[row] = s2; }
}

// ---------------------------------------------------------------- counting sort by dst
__global__ __launch_bounds__(256) void hist_kernel(
    const int* __restrict__ src, const int* __restrict__ dst, int E, int nloops,
    int Nd, int* __restrict__ offs) {
  extern __shared__ int bins[];
  int tot = E + nloops;
  int chunk = (tot + NB - 1) / NB;
  int b = blockIdx.x;
  int s0 = b * chunk, s1 = min(s0 + chunk, tot);
  for (int i = threadIdx.x; i < Nd; i += 256) bins[i] = 0;
  __syncthreads();
  for (int i = s0 + threadIdx.x; i < s1; i += 256) {
    int d = (i < E) ? dst[i] : (i - E);
    atomicAdd(&bins[d], 1);
  }
  __syncthreads();
  for (int i = threadIdx.x; i < Nd; i += 256) offs[(size_t)i * NB + b] = bins[i];
}

__global__ __launch_bounds__(256) void scan_bins_kernel(
    int* __restrict__ offs, int* __restrict__ binsum, int Nd) {
  int d = blockIdx.x * 4 + (threadIdx.x >> 6);
  if (d >= Nd) return;
  int lane = threadIdx.x & 63;
  int* p = offs + (size_t)d * NB;
  int v0 = p[2 * lane], v1 = p[2 * lane + 1];
  int s = v0 + v1;
  int t = s;
#pragma unroll
  for (int o = 1; o < 64; o <<= 1) { int u = __shfl_up(t, o); if (lane >= o) t += u; }
  int excl = t - s;
  p[2 * lane] = excl;
  p[2 * lane + 1] = excl + v0;
  if (lane == 63) binsum[d] = t;
}

// exclusive scan of binsum -> rowptr[0..Nd-1]; rowptr[Nd] = total
__global__ __launch_bounds__(256) void scan_base_kernel(
    const int* __restrict__ binsum, int* __restrict__ rowptr, int Nd) {
  __shared__ int wsum[4];
  __shared__ int carry;
  if (threadIdx.x == 0) carry = 0;
  __syncthreads();
  int lane = threadIdx.x & 63, w = threadIdx.x >> 6;
  for (int t0 = 0; t0 < Nd; t0 += 256) {
    int i = t0 + threadIdx.x;
    int v = (i < Nd) ? binsum[i] : 0;
    int t = v;
#pragma unroll
    for (int o = 1; o < 64; o <<= 1) { int u = __shfl_up(t, o); if (lane >= o) t += u; }
    if (lane == 63) wsum[w] = t;
    __syncthreads();
    int add = carry;
    for (int k = 0; k < w; ++k) add += wsum[k];
    if (i < Nd) rowptr[i] = t - v + add;
    __syncthreads();
    if (threadIdx.x == 0) carry += wsum[0] + wsum[1] + wsum[2] + wsum[3];
    __syncthreads();
  }
  if (threadIdx.x == 0) rowptr[Nd] = carry;
}

__global__ __launch_bounds__(256) void scatter_kernel(
    const int* __restrict__ src, const int* __restrict__ dst, int E, int nloops,
    int Nd, const int* __restrict__ offs, const int* __restrict__ rowptr,
    uint* __restrict__ sd) {
  extern __shared__ int bins[];
  int tot = E + nloops;
  int chunk = (tot + NB - 1) / NB;
  int b = blockIdx.x;
  int s0 = b * chunk, s1 = min(s0 + chunk, tot);
  for (int i = threadIdx.x; i < Nd; i += 256) bins[i] = 0;
  __syncthreads();
  for (int i = s0 + threadIdx.x; i < s1; i += 256) {
    int s_, d_;
    if (i < E) { s_ = src[i]; d_ = dst[i]; }
    else       { s_ = d_ = i - E; }
    int local = atomicAdd(&bins[d_], 1);
    int pos = rowptr[d_] + offs[(size_t)d_ * NB + b] + local;
    sd[pos] = (uint)s_ | ((uint)d_ << 16);
  }
}

// ---------------------------------------------------------------- fused GAT edge phase
// wave per dst: denom + aggregate(bf16 H) + bias + act + plane-write. No atomics, no fills.
// ACT: 0 = l2norm, 1 = relu
template <int ACT>
__global__ __launch_bounds__(256) void gat_agg_small(
    const int* __restrict__ rowptr, const uint* __restrict__ sd,
    const float* __restrict__ als, const float* __restrict__ ald,
    const ushort* __restrict__ Hb, const float* __restrict__ bias,
    uint* __restrict__ out_pl, int n) {
  int d = blockIdx.x * 4 + (threadIdx.x >> 6);
  if (d >= n) return;
  int lane = threadIdx.x & 63;
  int r0 = rowptr[d], r1 = rowptr[d + 1];
  float aldd = ald[d];
  // denom (lane-parallel)
  float dsum = 0.f;
  for (int j = r0 + lane; j < r1; j += 64) {
    float e = als[sd[j] & 0xffff] + aldd;
    e = (e > 0.f) ? e : NEG_SLOPE * e;
    dsum += __expf(e);
  }
#pragma unroll
  for (int o = 32; o; o >>= 1) dsum += __shfl_xor(dsum, o);
  float rden = 1.f / (dsum + 1e-16f);
  // aggregate: metadata fetched lane-parallel, broadcast by shuffle
  float4 acc = make_float4(0.f, 0.f, 0.f, 0.f);
  for (int b = r0; b < r1; b += 64) {
    int j = b + lane;
    float exv = 0.f; int srcv = 0;
    if (j < r1) {
      uint p = sd[j];
      srcv = p & 0xffff;
      float e = als[srcv] + aldd;
      e = (e > 0.f) ? e : NEG_SLOPE * e;
      exv = __expf(e);
    }
    int cnt = min(64, r1 - b);
    for (int t = 0; t < cnt; ++t) {
      float coef = __shfl(exv, t) * rden;
      int s = __shfl(srcv, t);
      ushort4 h = *(const ushort4*)(Hb + (size_t)s * HDIM + lane * 4);
      acc.x += coef * b2f(h.x);
      acc.y += coef * b2f(h.y);
      acc.z += coef * b2f(h.z);
      acc.w += coef * b2f(h.w);
    }
  }
  int c = lane * 4;
  float v0 = acc.x + bias[c], v1 = acc.y + bias[c + 1];
  float v2 = acc.z + bias[c + 2], v3 = acc.w + bias[c + 3];
  if (ACT == 1) {
    v0 = fmaxf(v0, 0.f); v1 = fmaxf(v1, 0.f);
    v2 = fmaxf(v2, 0.f); v3 = fmaxf(v3, 0.f);
  } else {
    float ss = v0 * v0 + v1 * v1 + v2 * v2 + v3 * v3;
#pragma unroll
    for (int o = 32; o; o >>= 1) ss += __shfl_xor(ss, o);
    float sc = 1.0f / fmaxf(sqrtf(ss), 1e-12f);
    v0 *= sc; v1 *= sc; v2 *= sc; v3 *= sc;
  }
  uint* o = out_pl + (size_t)d * HDIM + c;
  o[0] = f2pl(v0); o[1] = f2pl(v1); o[2] = f2pl(v2); o[3] = f2pl(v3);
}

// block per (dst, col-half) for few-dst / high-degree graphs (cp). relu only.
__global__ __launch_bounds__(256) void gat_agg_big(
    const int* __restrict__ rowptr, const uint* __restrict__ sd,
    const float* __restrict__ als, const float* __restrict__ ald,
    const ushort* __restrict__ Hb, const float* __restrict__ bias,
    uint* __restrict__ out_pl, int n) {
  int d = blockIdx.x >> 1;
  int half = blockIdx.x & 1;
  int tid = threadIdx.x;
  int lane = tid & 63, w = tid >> 6;
  int r0 = rowptr[d], r1 = rowptr[d + 1];
  float aldd = ald[d];
  // denom over 256 threads
  float dsum = 0.f;
  for (int j = r0 + tid; j < r1; j += 256) {
    float e = als[sd[j] & 0xffff] + aldd;
    e = (e > 0.f) ? e : NEG_SLOPE * e;
    dsum += __expf(e);
  }
#pragma unroll
  for (int o = 32; o; o >>= 1) dsum += __shfl_xor(dsum, o);
  __shared__ float wd[4];
  if (lane == 0) wd[w] = dsum;
  __syncthreads();
  float rden = 1.f / (wd[0] + wd[1] + wd[2] + wd[3] + 1e-16f);
  // each wave: contiguous edge slice, lanes cover 2 cols of this half
  int deg = r1 - r0;
  int per = (deg + 3) >> 2;
  int w0 = r0 + w * per, w1 = min(w0 + per, r1);
  int col = half * 128 + lane * 2;
  float2 acc = make_float2(0.f, 0.f);
  for (int b = w0; b < w1; b += 64) {
    int j = b + lane;
    float exv = 0.f; int srcv = 0;
    if (j < w1) {
      uint p = sd[j];
      srcv = p & 0xffff;
      float e = als[srcv] + aldd;
      e = (e > 0.f) ? e : NEG_SLOPE * e;
      exv = __expf(e);
    }
    int cnt = min(64, w1 - b);
    for (int t = 0; t < cnt; ++t) {
      float coef = __shfl(exv, t) * rden;
      int s = __shfl(srcv, t);
      ushort2 h = *(const ushort2*)(Hb + (size_t)s * HDIM + col);
      acc.x += coef * b2f(h.x);
      acc.y += coef * b2f(h.y);
    }
  }
  __shared__ float macc[4][130];
  macc[w][lane * 2] = acc.x;
  macc[w][lane * 2 + 1] = acc.y;
  __syncthreads();
  if (w == 0) {
#pragma unroll
    for (int u = 0; u < 2; ++u) {
      int cc = lane * 2 + u;
      float s = macc[0][cc] + macc[1][cc] + macc[2][cc] + macc[3][cc];
      float v = fmaxf(s + bias[half * 128 + cc], 0.f);
      out_pl[(size_t)d * HDIM + half * 128 + cc] = f2pl(v);
    }
  }
}

// ---------------------------------------------------------------- head
template <int IN_PL>
__global__ __launch_bounds__(256) void l2norm_pl_kernel(
    const void* __restrict__ in, const float* __restrict__ bias,
    uint* __restrict__ out_pl, int n) {
  int row = blockIdx.x * 4 + (threadIdx.x >> 6);
  if (row >= n) return;
  int lane = threadIdx.x & 63;
  float v[4];
  float ss = 0.f;
#pragma unroll
  for (int u = 0; u < 4; ++u) {
    int c = lane + u * 64;
    float t = IN_PL ? pl2f(((const uint*)in)[(size_t)row * HDIM + c])
                    : ((const float*)in)[(size_t)row * HDIM + c];
    if (bias) t += bias[c];
    v[u] = t;
    ss += t * t;
  }
#pragma unroll
  for (int off = 32; off; off >>= 1) ss += __shfl_xor(ss, off);
  float sc = 1.0f / fmaxf(sqrtf(ss), 1e-12f);
#pragma unroll
  for (int u = 0; u < 4; ++u) {
    int c = lane + u * 64;
    out_pl[(size_t)row * HDIM + c] = f2pl(v[u] * sc);
  }
}

__global__ __launch_bounds__(256) void head3_kernel(
    const float* __restrict__ h2, const float* __restrict__ W3, const float* __restrict__ b3,
    float* __restrict__ out, int M, int K) {
  int i = blockIdx.x * 4 + (threadIdx.x >> 6);
  int lane = threadIdx.x & 63;
  if (i >= M) return;
  float s0 = 0.f, s1 = 0.f;
  for (int k = lane; k < K; k += 64) {
    float h = h2[(size_t)i * K + k];
    s0 += h * W3[k * 2 + 0];
    s1 += h * W3[k * 2 + 1];
  }
#pragma unroll
  for (int off = 32; off; off >>= 1) {
    s0 += __shfl_down(s0, off);
    s1 += __shfl_down(s1, off);
  }
  if (lane == 0) {
    out[(size_t)i * 2 + 0] = s0 + b3[0];
    out[(size_t)i * 2 + 1] = s1 + b3[1];
  }
}

// ---------------------------------------------------------------- host side
static void build_sorted(hipStream_t stream,
                         const int* src, const int* dst, int E, int nloops, int Nd,
                         int* offs, int* binsum, int* rowptr, uint* sd) {
  size_t lds = (size_t)Nd * sizeof(int);
  hist_kernel<<<NB, 256, lds, stream>>>(src, dst, E, nloops, Nd, offs);
  scan_bins_kernel<<<cdiv(Nd, 4), 256, 0, stream>>>(offs, binsum, Nd);
  scan_base_kernel<<<1, 256, 0, stream>>>(binsum, rowptr, Nd);
  scatter_kernel<<<NB, 256, lds, stream>>>(src, dst, E, nloops, Nd, offs, rowptr, sd);
}

struct GatBufs {
  float *Hsrc, *Hdst, *als, *ald;
  ushort* Hb;
};

static void run_gat(hipStream_t stream,
                    const void* Xsrc, int src_mode, int Ns,
                    const void* Xdst, int dst_mode, int Nd, bool same,
                    const uint* WT, const float* asrc, const float* adst, const float* bias,
                    const uint* sd, const int* rowptr,
                    const GatBufs& b, uint* xout_pl, int act /*0=l2norm,1=relu*/) {
  // H_src = X_src @ W (fp32 + bf16 copy for gather)
  launch_gemm(stream, src_mode, 2, 0, Xsrc, nullptr, nullptr, nullptr, nullptr, nullptr, 0,
              WT, nullptr, b.Hsrc, b.Hb, Ns, HDIM, HDIM);
  if (same) {
    rowdot2_kernel<<<cdiv(Ns, 4), 256, 0, stream>>>(b.Hsrc, asrc, adst, b.als, b.ald, Ns);
  } else {
    launch_gemm(stream, dst_mode, 0, 0, Xdst, nullptr, nullptr, nullptr, nullptr, nullptr, 0,
                WT, nullptr, b.Hdst, nullptr, Nd, HDIM, HDIM);
    rowdot_kernel<<<cdiv(Ns, 4), 256, 0, stream>>>(b.Hsrc, asrc, b.als, Ns);
    rowdot_kernel<<<cdiv(Nd, 4), 256, 0, stream>>>(b.Hdst, adst, b.ald, Nd);
  }
  if (Nd <= 256) {
    gat_agg_big<<<Nd * 2, 256, 0, stream>>>(rowptr, sd, b.als, b.ald, b.Hb, bias, xout_pl, Nd);
  } else if (act == 0) {
    gat_agg_small<0><<<cdiv(Nd, 4), 256, 0, stream>>>(rowptr, sd, b.als, b.ald, b.Hb, bias, xout_pl, Nd);
  } else {
    gat_agg_small<1><<<cdiv(Nd, 4), 256, 0, stream>>>(rowptr, sd, b.als, b.ald, b.Hb, bias, xout_pl, Nd);
  }
}

extern "C" void kernel_launch(void* const* d_in, const int* in_sizes, int n_in,
                              void* d_out, int out_size, void* d_ws, size_t ws_size,
                              hipStream_t stream) {
  const float* drug_emb = (const float*)d_in[0];
  const float* prot_emb = (const float*)d_in[1];
  const float* cell_emb = (const float*)d_in[2];
  const float* W_pp = (const float*)d_in[3];
  const float* as_pp = (const float*)d_in[4];
  const float* ad_pp = (const float*)d_in[5];
  const float* b_pp = (const float*)d_in[6];
  const float* W_dp = (const float*)d_in[7];
  const float* as_dp = (const float*)d_in[8];
  const float* ad_dp = (const float*)d_in[9];
  const float* b_dp = (const float*)d_in[10];
  const float* W_cp = (const float*)d_in[11];
  const float* as_cp = (const float*)d_in[12];
  const float* ad_cp = (const float*)d_in[13];
  const float* b_cp = (const float*)d_in[14];
  const float* W1 = (const float*)d_in[15];
  const float* b1 = (const float*)d_in[16];
  const float* W2 = (const float*)d_in[17];
  const float* b2 = (const float*)d_in[18];
  const float* W3 = (const float*)d_in[19];
  const float* b3 = (const float*)d_in[20];
  const int* edge_pp = (const int*)d_in[21];
  const int* edge_dp = (const int*)d_in[22];
  const int* edge_cp = (const int*)d_in[23];
  const int* drug1 = (const int*)d_in[24];
  const int* drug2 = (const int*)d_in[25];
  const int* cellb = (const int*)d_in[26];

  const int ND = in_sizes[0] / HDIM;   // 2000
  const int NP = in_sizes[1] / HDIM;   // 19000
  const int NC = in_sizes[2] / HDIM;   // 100
  const int L = in_sizes[3] / (HDIM * HDIM);  // 2
  const int E_pp = in_sizes[21] / 2;
  const int E_dp = in_sizes[22] / 2;
  const int E_cp = in_sizes[23] / 2;
  const int B = in_sizes[24];          // 8192

  const int* src_pp = edge_pp;          const int* dst_pp = edge_pp + E_pp;
  const int* src_dp = edge_dp;          const int* dst_dp = edge_dp + E_dp;
  const int* src_cp = edge_cp;          const int* dst_cp = edge_cp + E_cp;
  const int tot_pp = E_pp + NP, tot_dp = E_dp, tot_cp = E_cp;

  // ---------------- workspace (~70 MB peak)
  float* ws = (float*)d_ws;
  size_t off = 0;
  auto alloc = [&](size_t n) { float* p = ws + off; off += (n + 3) & ~(size_t)3; return p; };
  int maxN = NP > ND ? NP : ND; if (NC > maxN) maxN = NC;

  uint* xp_pl  = (uint*)alloc((size_t)NP * HDIM);
  uint* xd_pl  = (uint*)alloc((size_t)ND * HDIM);
  uint* xc_pl  = (uint*)alloc((size_t)NC * HDIM);
  uint* xdn_pl = (uint*)alloc((size_t)ND * HDIM);
  uint* xcn_pl = (uint*)alloc((size_t)NC * HDIM);
  uint* WTpp = (uint*)alloc((size_t)L * HDIM * HDIM);
  uint* WTdp = (uint*)alloc((size_t)L * HDIM * HDIM);
  uint* WTcp = (uint*)alloc((size_t)L * HDIM * HDIM);
  int* binsum = (int*)alloc(maxN);
  int* rp_pp = (int*)alloc(NP + 1);
  int* rp_dp = (int*)alloc(ND + 1);
  int* rp_cp = (int*)alloc(NC + 1);
  uint* sd_pp = (uint*)alloc(tot_pp);
  uint* sd_dp = (uint*)alloc(tot_dp);
  uint* sd_cp = (uint*)alloc(tot_cp);

  // scratch region S: graph bufs <-> offs (sort) <-> MLP bufs
  size_t S0 = off;
  float* Hp = ws + S0;
  float* Hd = Hp + (size_t)NP * HDIM;
  ushort* Hb = (ushort*)(Hd + (size_t)ND * HDIM);
  float* als = (float*)(Hb + (size_t)NP * HDIM);
  float* ald = als + maxN;
  // MLP overlay
  uint* W1T = (uint*)(ws + S0);                       // [1536][768]
  uint* W2T = W1T + (size_t)768 * 1536;               // [512][1536]
  const int CH = 4096;
  uint* h1_pl = W2T + (size_t)1536 * 512;             // [CH][1536] planes
  float* h2 = (float*)(h1_pl + (size_t)CH * 1536);    // [CH][512] fp32
  (void)ws_size; (void)n_in; (void)out_size;

  // ---- sort builds (offs overlays S; dead before Hp first written)
  int* offs = (int*)(ws + S0);
  build_sorted(stream, src_pp, dst_pp, E_pp, NP, NP, offs, binsum, rp_pp, sd_pp);
  build_sorted(stream, src_dp, dst_dp, E_dp, 0, ND, offs, binsum, rp_dp, sd_dp);
  build_sorted(stream, src_cp, dst_cp, E_cp, 0, NC, offs, binsum, rp_cp, sd_cp);

  // ---- weight planes (transposed)
  for (int l = 0; l < L; ++l) {
    int WOFF = l * HDIM * HDIM;
    wconv_kernel<<<cdiv(HDIM * HDIM, 256), 256, 0, stream>>>(W_pp + WOFF, WTpp + WOFF, HDIM, HDIM);
    wconv_kernel<<<cdiv(HDIM * HDIM, 256), 256, 0, stream>>>(W_dp + WOFF, WTdp + WOFF, HDIM, HDIM);
    wconv_kernel<<<cdiv(HDIM * HDIM, 256), 256, 0, stream>>>(W_cp + WOFF, WTcp + WOFF, HDIM, HDIM);
  }

  GatBufs gb{Hp, Hd, als, ald, Hb};

  for (int l = 0; l < L; ++l) {
    const int WOFF = l * HDIM * HDIM, VOFF = l * HDIM;
    run_gat(stream,
            l == 0 ? (const void*)prot_emb : (const void*)xp_pl, l == 0 ? 1 : 0, NP,
            nullptr, 0, NP, /*same=*/true,
            WTpp + WOFF, as_pp + VOFF, ad_pp + VOFF, b_pp + VOFF,
            sd_pp, rp_pp, gb, xp_pl, 0);
    run_gat(stream, xp_pl, 0, NP,
            l == 0 ? (const void*)drug_emb : (const void*)xd_pl, l == 0 ? 1 : 0, ND, false,
            WTdp + WOFF, as_dp + VOFF, ad_dp + VOFF, b_dp + VOFF,
            sd_dp, rp_dp, gb, xd_pl, 1);
    run_gat(stream, xp_pl, 0, NP,
            l == 0 ? (const void*)cell_emb : (const void*)xc_pl, l == 0 ? 1 : 0, NC, false,
            WTcp + WOFF, as_cp + VOFF, ad_cp + VOFF, b_cp + VOFF,
            sd_cp, rp_cp, gb, xc_pl, 1);
  }

  // ---------------- head
  l2norm_pl_kernel<1><<<cdiv(ND, 4), 256, 0, stream>>>(xd_pl, nullptr, xdn_pl, ND);
  l2norm_pl_kernel<1><<<cdiv(NC, 4), 256, 0, stream>>>(xc_pl, nullptr, xcn_pl, NC);

  wconv_kernel<<<cdiv(768 * 1536, 256), 256, 0, stream>>>(W1, W1T, 768, 1536);
  wconv_kernel<<<cdiv(1536 * 512, 256), 256, 0, stream>>>(W2, W2T, 1536, 512);

  float* outp = (float*)d_out;
  for (int c0 = 0; c0 < B; c0 += CH) {
    int M = (B - c0) < CH ? (B - c0) : CH;
    launch_gemm(stream, 2, 1, 1, nullptr, xdn_pl, xcn_pl, drug1, drug2, cellb, c0,
                W1T, b1, h1_pl, nullptr, M, 1536, 768);
    launch_gemm(stream, 0, 0, 1, h1_pl, nullptr, nullptr, nullptr, nullptr, nullptr, 0,
                W2T, b2, h2, nullptr, M, 512, 1536);
    head3_kernel<<<cdiv(M, 4), 256, 0, stream>>>(h2, W3, b3, outp + (size_t)c0 * 2, M, 512);
  }
}

// Round 8
// 1058.658 us; speedup vs baseline: 4.7937x; 1.3392x over previous
//
#include <hip/hip_runtime.h>
#include <hip/hip_bf16.h>

#define HDIM 256
#define NEG_SLOPE 0.2f
#define NB 128          // blocks for hist/scatter
#define SLICES 8        // edge slices per dst in the big-degree aggregator

typedef __attribute__((ext_vector_type(8))) short bf16x8;
typedef __attribute__((ext_vector_type(4))) float f32x4;

// split-bf16 "plane": uint = hi | (lo<<16), x ~= bf16(hi) + bf16(lo)
__device__ inline uint f2pl(float x) {
  __hip_bfloat16 h = __float2bfloat16(x);
  ushort hi = *(ushort*)&h;
  float r = x - __bfloat162float(h);
  __hip_bfloat16 l = __float2bfloat16(r);
  ushort lo = *(ushort*)&l;
  return (uint)hi | ((uint)lo << 16);
}
__device__ inline float pl2f(uint p) {
  ushort hi = (ushort)(p & 0xffff), lo = (ushort)(p >> 16);
  return __bfloat162float(*(__hip_bfloat16*)&hi) + __bfloat162float(*(__hip_bfloat16*)&lo);
}
__device__ inline ushort f2b(float x) {
  __hip_bfloat16 h = __float2bfloat16(x);
  return *(ushort*)&h;
}
__device__ inline float b2f(ushort u) {
  uint x = ((uint)u) << 16;
  return __int_as_float((int)x);
}

static inline int cdiv(int a, int b) { return (a + b - 1) / b; }

// ---------------------------------------------------------------- utilities
__global__ void fillf_kernel(float* __restrict__ p, float v, int n) {
  int i = blockIdx.x * blockDim.x + threadIdx.x;
  if (i < n) p[i] = v;
}

// W[K][N] fp32 -> WT[N][K] planes
__global__ void wconv_kernel(const float* __restrict__ W, uint* __restrict__ WT,
                             int K, int N) {
  int i = blockIdx.x * 256 + threadIdx.x;
  if (i >= K * N) return;
  int k = i / N, n = i - k * N;
  WT[(size_t)n * K + k] = f2pl(W[i]);
}

// ---------------------------------------------------------------- MFMA GEMM
// C = act(A@B + bias). B pre-transposed planes [N][K].
// AMODE: 0 planes A; 1 fp32 A; 2 gathered planes.
// OUTMODE: 0 fp32 C; 1 plane C; 2 fp32 C + bf16 copy Cb.
#define TBM 128
#define TBN 64
#define TBK 32
#define PITCH 40

template <int AMODE, int OUTMODE, int ACT>
__global__ __launch_bounds__(256) void mfma_gemm(
    const void* __restrict__ Av,
    const uint* __restrict__ xdn_pl, const uint* __restrict__ xcn_pl,
    const int* __restrict__ g1, const int* __restrict__ g2, const int* __restrict__ g3,
    int row0,
    const uint* __restrict__ BT, const float* __restrict__ bias,
    void* __restrict__ Cv, ushort* __restrict__ Cb, int M, int N, int K) {
  __shared__ ushort Ah[TBM][PITCH];
  __shared__ ushort Al[TBM][PITCH];
  __shared__ ushort Bh[TBN][PITCH];
  __shared__ ushort Bl[TBN][PITCH];

  const int tid = threadIdx.x;
  const int lane = tid & 63;
  const int wid = tid >> 6;
  const int wm = wid & 1, wn = wid >> 1;
  const int l16 = lane & 15;
  const int quad = lane >> 4;
  const int m0 = blockIdx.y * TBM;
  const int n0 = blockIdx.x * TBN;

  const int am = tid >> 1;
  const int ah = (tid & 1) * 16;
  const int bn = tid >> 2;
  const int bq = (tid & 3) * 8;

  f32x4 acc[4][2];
#pragma unroll
  for (int i = 0; i < 4; ++i)
#pragma unroll
    for (int j = 0; j < 2; ++j) acc[i][j] = (f32x4){0.f, 0.f, 0.f, 0.f};

  for (int k0 = 0; k0 < K; k0 += TBK) {
    __syncthreads();
    {
      int gm = m0 + am;
      if (AMODE == 1) {
        const float* A = (const float*)Av;
        const float* ap = (gm < M) ? A + (size_t)gm * K + k0 + ah : nullptr;
#pragma unroll
        for (int u = 0; u < 4; ++u) {
          float4 v = ap ? *(const float4*)(ap + u * 4) : make_float4(0.f, 0.f, 0.f, 0.f);
          uint p0 = f2pl(v.x), p1 = f2pl(v.y), p2 = f2pl(v.z), p3 = f2pl(v.w);
          ushort4 h = {(ushort)(p0 & 0xffff), (ushort)(p1 & 0xffff), (ushort)(p2 & 0xffff), (ushort)(p3 & 0xffff)};
          ushort4 l = {(ushort)(p0 >> 16), (ushort)(p1 >> 16), (ushort)(p2 >> 16), (ushort)(p3 >> 16)};
          *(ushort4*)&Ah[am][ah + u * 4] = h;
          *(ushort4*)&Al[am][ah + u * 4] = l;
        }
      } else {
        const uint* ap = nullptr;
        if (gm < M) {
          if (AMODE == 2) {
            int bi = row0 + gm;
            int seg = k0 >> 8;
            int idx = (seg == 0) ? g1[bi] : (seg == 1 ? g2[bi] : g3[bi]);
            ap = ((seg == 2) ? xcn_pl : xdn_pl) + (size_t)idx * HDIM + (k0 & 255) + ah;
          } else {
            ap = (const uint*)Av + (size_t)gm * K + k0 + ah;
          }
        }
#pragma unroll
        for (int u = 0; u < 4; ++u) {
          uint4 v = ap ? *(const uint4*)(ap + u * 4) : make_uint4(0, 0, 0, 0);
          ushort4 h = {(ushort)(v.x & 0xffff), (ushort)(v.y & 0xffff), (ushort)(v.z & 0xffff), (ushort)(v.w & 0xffff)};
          ushort4 l = {(ushort)(v.x >> 16), (ushort)(v.y >> 16), (ushort)(v.z >> 16), (ushort)(v.w >> 16)};
          *(ushort4*)&Ah[am][ah + u * 4] = h;
          *(ushort4*)&Al[am][ah + u * 4] = l;
        }
      }
    }
    {
      const uint* bp = BT + (size_t)(n0 + bn) * K + k0 + bq;
#pragma unroll
      for (int u = 0; u < 2; ++u) {
        uint4 v = *(const uint4*)(bp + u * 4);
        ushort4 h = {(ushort)(v.x & 0xffff), (ushort)(v.y & 0xffff), (ushort)(v.z & 0xffff), (ushort)(v.w & 0xffff)};
        ushort4 l = {(ushort)(v.x >> 16), (ushort)(v.y >> 16), (ushort)(v.z >> 16), (ushort)(v.w >> 16)};
        *(ushort4*)&Bh[bn][bq + u * 4] = h;
        *(ushort4*)&Bl[bn][bq + u * 4] = l;
      }
    }
    __syncthreads();

    bf16x8 ahf[4], alf[4], bhf[2], blf[2];
#pragma unroll
    for (int t = 0; t < 4; ++t) {
      int r = wm * 64 + t * 16 + l16;
      ahf[t] = *(const bf16x8*)&Ah[r][quad * 8];
      alf[t] = *(const bf16x8*)&Al[r][quad * 8];
    }
#pragma unroll
    for (int t = 0; t < 2; ++t) {
      int r = wn * 32 + t * 16 + l16;
      bhf[t] = *(const bf16x8*)&Bh[r][quad * 8];
      blf[t] = *(const bf16x8*)&Bl[r][quad * 8];
    }
#pragma unroll
    for (int tm = 0; tm < 4; ++tm)
#pragma unroll
      for (int tn = 0; tn < 2; ++tn) {
        acc[tm][tn] = __builtin_amdgcn_mfma_f32_16x16x32_bf16(ahf[tm], bhf[tn], acc[tm][tn], 0, 0, 0);
        acc[tm][tn] = __builtin_amdgcn_mfma_f32_16x16x32_bf16(ahf[tm], blf[tn], acc[tm][tn], 0, 0, 0);
        acc[tm][tn] = __builtin_amdgcn_mfma_f32_16x16x32_bf16(alf[tm], bhf[tn], acc[tm][tn], 0, 0, 0);
      }
  }

#pragma unroll
  for (int tn = 0; tn < 2; ++tn) {
    int col = n0 + wn * 32 + tn * 16 + l16;
    float bv = bias ? bias[col] : 0.f;
#pragma unroll
    for (int tm = 0; tm < 4; ++tm) {
#pragma unroll
      for (int r = 0; r < 4; ++r) {
        int row = m0 + wm * 64 + tm * 16 + quad * 4 + r;
        if (row >= M) continue;
        float v = acc[tm][tn][r] + bv;
        if (ACT == 1) v = fmaxf(v, 0.f);
        if (OUTMODE == 1) ((uint*)Cv)[(size_t)row * N + col] = f2pl(v);
        else {
          ((float*)Cv)[(size_t)row * N + col] = v;
          if (OUTMODE == 2) Cb[(size_t)row * N + col] = f2b(v);
        }
      }
    }
  }
}

static void launch_gemm(hipStream_t s, int amode, int outmode, int act,
                        const void* A, const uint* xdn, const uint* xcn,
                        const int* g1, const int* g2, const int* g3, int row0,
                        const uint* BT, const float* bias, void* C, ushort* Cb,
                        int M, int N, int K) {
  dim3 g(N / TBN, cdiv(M, TBM));
  if (amode == 2)
    mfma_gemm<2, 1, 1><<<g, 256, 0, s>>>(A, xdn, xcn, g1, g2, g3, row0, BT, bias, C, Cb, M, N, K);
  else if (amode == 1 && outmode == 2)
    mfma_gemm<1, 2, 0><<<g, 256, 0, s>>>(A, xdn, xcn, g1, g2, g3, row0, BT, bias, C, Cb, M, N, K);
  else if (amode == 1)
    mfma_gemm<1, 0, 0><<<g, 256, 0, s>>>(A, xdn, xcn, g1, g2, g3, row0, BT, bias, C, Cb, M, N, K);
  else if (outmode == 2)
    mfma_gemm<0, 2, 0><<<g, 256, 0, s>>>(A, xdn, xcn, g1, g2, g3, row0, BT, bias, C, Cb, M, N, K);
  else if (act == 1)
    mfma_gemm<0, 0, 1><<<g, 256, 0, s>>>(A, xdn, xcn, g1, g2, g3, row0, BT, bias, C, Cb, M, N, K);
  else
    mfma_gemm<0, 0, 0><<<g, 256, 0, s>>>(A, xdn, xcn, g1, g2, g3, row0, BT, bias, C, Cb, M, N, K);
}

// ---------------------------------------------------------------- row dots
__global__ __launch_bounds__(256) void rowdot_kernel(
    const float* __restrict__ H, const float* __restrict__ a,
    float* __restrict__ out, int n) {
  int row = blockIdx.x * 4 + (threadIdx.x >> 6);
  if (row >= n) return;
  int lane = threadIdx.x & 63;
  const float* h = H + (size_t)row * HDIM;
  float s = 0.f;
#pragma unroll
  for (int u = 0; u < 4; ++u) {
    int c = lane + u * 64;
    s += h[c] * a[c];
  }
#pragma unroll
  for (int off = 32; off; off >>= 1) s += __shfl_down(s, off);
  if (lane == 0) out[row] = s;
}

__global__ __launch_bounds__(256) void rowdot2_kernel(
    const float* __restrict__ H, const float* __restrict__ a1, const float* __restrict__ a2,
    float* __restrict__ o1, float* __restrict__ o2, int n) {
  int row = blockIdx.x * 4 + (threadIdx.x >> 6);
  if (row >= n) return;
  int lane = threadIdx.x & 63;
  const float* h = H + (size_t)row * HDIM;
  float s1 = 0.f, s2 = 0.f;
#pragma unroll
  for (int u = 0; u < 4; ++u) {
    int c = lane + u * 64;
    float hv = h[c];
    s1 += hv * a1[c];
    s2 += hv * a2[c];
  }
#pragma unroll
  for (int off = 32; off; off >>= 1) {
    s1 += __shfl_down(s1, off);
    s2 += __shfl_down(s2, off);
  }
  if (lane == 0) { o1[row] = s1; o2[row] = s2; }
}

// ---------------------------------------------------------------- counting sort by dst
__global__ __launch_bounds__(256) void hist_kernel(
    const int* __restrict__ src, const int* __restrict__ dst, int E, int nloops,
    int Nd, int* __restrict__ offs) {
  extern __shared__ int bins[];
  int tot = E + nloops;
  int chunk = (tot + NB - 1) / NB;
  int b = blockIdx.x;
  int s0 = b * chunk, s1 = min(s0 + chunk, tot);
  for (int i = threadIdx.x; i < Nd; i += 256) bins[i] = 0;
  __syncthreads();
  for (int i = s0 + threadIdx.x; i < s1; i += 256) {
    int d = (i < E) ? dst[i] : (i - E);
    atomicAdd(&bins[d], 1);
  }
  __syncthreads();
  for (int i = threadIdx.x; i < Nd; i += 256) offs[(size_t)i * NB + b] = bins[i];
}

__global__ __launch_bounds__(256) void scan_bins_kernel(
    int* __restrict__ offs, int* __restrict__ binsum, int Nd) {
  int d = blockIdx.x * 4 + (threadIdx.x >> 6);
  if (d >= Nd) return;
  int lane = threadIdx.x & 63;
  int* p = offs + (size_t)d * NB;
  int v0 = p[2 * lane], v1 = p[2 * lane + 1];
  int s = v0 + v1;
  int t = s;
#pragma unroll
  for (int o = 1; o < 64; o <<= 1) { int u = __shfl_up(t, o); if (lane >= o) t += u; }
  int excl = t - s;
  p[2 * lane] = excl;
  p[2 * lane + 1] = excl + v0;
  if (lane == 63) binsum[d] = t;
}

__global__ __launch_bounds__(256) void scan_base_kernel(
    const int* __restrict__ binsum, int* __restrict__ rowptr, int Nd) {
  __shared__ int wsum[4];
  __shared__ int carry;
  if (threadIdx.x == 0) carry = 0;
  __syncthreads();
  int lane = threadIdx.x & 63, w = threadIdx.x >> 6;
  for (int t0 = 0; t0 < Nd; t0 += 256) {
    int i = t0 + threadIdx.x;
    int v = (i < Nd) ? binsum[i] : 0;
    int t = v;
#pragma unroll
    for (int o = 1; o < 64; o <<= 1) { int u = __shfl_up(t, o); if (lane >= o) t += u; }
    if (lane == 63) wsum[w] = t;
    __syncthreads();
    int add = carry;
    for (int k = 0; k < w; ++k) add += wsum[k];
    if (i < Nd) rowptr[i] = t - v + add;
    __syncthreads();
    if (threadIdx.x == 0) carry += wsum[0] + wsum[1] + wsum[2] + wsum[3];
    __syncthreads();
  }
  if (threadIdx.x == 0) rowptr[Nd] = carry;
}

__global__ __launch_bounds__(256) void scatter_kernel(
    const int* __restrict__ src, const int* __restrict__ dst, int E, int nloops,
    int Nd, const int* __restrict__ offs, const int* __restrict__ rowptr,
    uint* __restrict__ sd) {
  extern __shared__ int bins[];
  int tot = E + nloops;
  int chunk = (tot + NB - 1) / NB;
  int b = blockIdx.x;
  int s0 = b * chunk, s1 = min(s0 + chunk, tot);
  for (int i = threadIdx.x; i < Nd; i += 256) bins[i] = 0;
  __syncthreads();
  for (int i = s0 + threadIdx.x; i < s1; i += 256) {
    int s_, d_;
    if (i < E) { s_ = src[i]; d_ = dst[i]; }
    else       { s_ = d_ = i - E; }
    int local = atomicAdd(&bins[d_], 1);
    int pos = rowptr[d_] + offs[(size_t)d_ * NB + b] + local;
    sd[pos] = (uint)s_ | ((uint)d_ << 16);
  }
}

// ---------------------------------------------------------------- fused GAT edge phase
// wave per dst; ×8-batched shuffle-broadcast so 8 gathers are in flight.
// ACT: 0 = l2norm, 1 = relu
template <int ACT>
__global__ __launch_bounds__(256) void gat_agg_small(
    const int* __restrict__ rowptr, const uint* __restrict__ sd,
    const float* __restrict__ als, const float* __restrict__ ald,
    const ushort* __restrict__ Hb, const float* __restrict__ bias,
    uint* __restrict__ out_pl, int n) {
  int d = blockIdx.x * 4 + (threadIdx.x >> 6);
  if (d >= n) return;
  int lane = threadIdx.x & 63;
  int r0 = rowptr[d], r1 = rowptr[d + 1];
  float aldd = ald[d];
  float dsum = 0.f;
  for (int j = r0 + lane; j < r1; j += 64) {
    float e = als[sd[j] & 0xffff] + aldd;
    e = (e > 0.f) ? e : NEG_SLOPE * e;
    dsum += __expf(e);
  }
#pragma unroll
  for (int o = 32; o; o >>= 1) dsum += __shfl_xor(dsum, o);
  float rden = 1.f / (dsum + 1e-16f);

  float4 acc = make_float4(0.f, 0.f, 0.f, 0.f);
  for (int b = r0; b < r1; b += 64) {
    int j = b + lane;
    float exv = 0.f; int srcv = 0;
    if (j < r1) {
      uint p = sd[j];
      srcv = p & 0xffff;
      float e = als[srcv] + aldd;
      e = (e > 0.f) ? e : NEG_SLOPE * e;
      exv = __expf(e) * rden;      // rden folded: broadcast value is final coef
    }
    int cnt = min(64, r1 - b);
    for (int t0 = 0; t0 < cnt; t0 += 8) {
      float cf[8]; int sv[8];
#pragma unroll
      for (int u = 0; u < 8; ++u) {
        cf[u] = __shfl(exv, t0 + u);       // OOB lanes carry coef 0 -> safe
        sv[u] = __shfl(srcv, t0 + u);
      }
      ushort4 hv[8];
#pragma unroll
      for (int u = 0; u < 8; ++u)
        hv[u] = *(const ushort4*)(Hb + (size_t)sv[u] * HDIM + lane * 4);
#pragma unroll
      for (int u = 0; u < 8; ++u) {
        acc.x += cf[u] * b2f(hv[u].x);
        acc.y += cf[u] * b2f(hv[u].y);
        acc.z += cf[u] * b2f(hv[u].z);
        acc.w += cf[u] * b2f(hv[u].w);
      }
    }
  }
  int c = lane * 4;
  float v0 = acc.x + bias[c], v1 = acc.y + bias[c + 1];
  float v2 = acc.z + bias[c + 2], v3 = acc.w + bias[c + 3];
  if (ACT == 1) {
    v0 = fmaxf(v0, 0.f); v1 = fmaxf(v1, 0.f);
    v2 = fmaxf(v2, 0.f); v3 = fmaxf(v3, 0.f);
  } else {
    float ss = v0 * v0 + v1 * v1 + v2 * v2 + v3 * v3;
#pragma unroll
    for (int o = 32; o; o >>= 1) ss += __shfl_xor(ss, o);
    float sc = 1.0f / fmaxf(sqrtf(ss), 1e-12f);
    v0 *= sc; v1 *= sc; v2 *= sc; v3 *= sc;
  }
  uint* o = out_pl + (size_t)d * HDIM + c;
  o[0] = f2pl(v0); o[1] = f2pl(v1); o[2] = f2pl(v2); o[3] = f2pl(v3);
}

// high-degree / few-dst graphs (cp): block per (dst, edge-slice); full-row waves;
// coalesced fp32 atomic partials into out32 (zeroed); finish kernel applies bias+relu.
__global__ __launch_bounds__(256) void gat_agg_slice(
    const int* __restrict__ rowptr, const uint* __restrict__ sd,
    const float* __restrict__ als, const float* __restrict__ ald,
    const ushort* __restrict__ Hb, float* __restrict__ out32, int n) {
  int d = blockIdx.x / SLICES;
  int sl = blockIdx.x - d * SLICES;
  if (d >= n) return;
  int lane = threadIdx.x & 63, w = threadIdx.x >> 6;
  int r0 = rowptr[d], r1 = rowptr[d + 1];
  float aldd = ald[d];
  // denom over all edges of dst (256 threads)
  float dsum = 0.f;
  for (int j = r0 + threadIdx.x; j < r1; j += 256) {
    float e = als[sd[j] & 0xffff] + aldd;
    e = (e > 0.f) ? e : NEG_SLOPE * e;
    dsum += __expf(e);
  }
#pragma unroll
  for (int o = 32; o; o >>= 1) dsum += __shfl_xor(dsum, o);
  __shared__ float wd[4];
  if (lane == 0) wd[w] = dsum;
  __syncthreads();
  float rden = 1.f / (wd[0] + wd[1] + wd[2] + wd[3] + 1e-16f);
  // this block's slice, split across 4 waves
  int deg = r1 - r0;
  int per_b = (deg + SLICES - 1) / SLICES;
  int b0 = r0 + sl * per_b, b1 = min(b0 + per_b, r1);
  int wdeg = b1 - b0;
  if (wdeg <= 0) return;
  int per_w = (wdeg + 3) >> 2;
  int w0 = b0 + w * per_w, w1 = min(w0 + per_w, b1);

  float4 acc = make_float4(0.f, 0.f, 0.f, 0.f);
  for (int b = w0; b < w1; b += 64) {
    int j = b + lane;
    float exv = 0.f; int srcv = 0;
    if (j < w1) {
      uint p = sd[j];
      srcv = p & 0xffff;
      float e = als[srcv] + aldd;
      e = (e > 0.f) ? e : NEG_SLOPE * e;
      exv = __expf(e) * rden;
    }
    int cnt = min(64, w1 - b);
    for (int t0 = 0; t0 < cnt; t0 += 8) {
      float cf[8]; int sv[8];
#pragma unroll
      for (int u = 0; u < 8; ++u) {
        cf[u] = __shfl(exv, t0 + u);
        sv[u] = __shfl(srcv, t0 + u);
      }
      ushort4 hv[8];
#pragma unroll
      for (int u = 0; u < 8; ++u)
        hv[u] = *(const ushort4*)(Hb + (size_t)sv[u] * HDIM + lane * 4);
#pragma unroll
      for (int u = 0; u < 8; ++u) {
        acc.x += cf[u] * b2f(hv[u].x);
        acc.y += cf[u] * b2f(hv[u].y);
        acc.z += cf[u] * b2f(hv[u].z);
        acc.w += cf[u] * b2f(hv[u].w);
      }
    }
  }
  float* o = out32 + (size_t)d * HDIM + lane * 4;
  atomicAdd(o + 0, acc.x); atomicAdd(o + 1, acc.y);
  atomicAdd(o + 2, acc.z); atomicAdd(o + 3, acc.w);
}

__global__ void finish_relu_pl(const float* __restrict__ acc, const float* __restrict__ bias,
                               uint* __restrict__ out_pl, int total) {
  int i = blockIdx.x * blockDim.x + threadIdx.x;
  if (i >= total) return;
  int c = i & (HDIM - 1);
  out_pl[i] = f2pl(fmaxf(acc[i] + bias[c], 0.f));
}

// ---------------------------------------------------------------- head
template <int IN_PL>
__global__ __launch_bounds__(256) void l2norm_pl_kernel(
    const void* __restrict__ in, const float* __restrict__ bias,
    uint* __restrict__ out_pl, int n) {
  int row = blockIdx.x * 4 + (threadIdx.x >> 6);
  if (row >= n) return;
  int lane = threadIdx.x & 63;
  float v[4];
  float ss = 0.f;
#pragma unroll
  for (int u = 0; u < 4; ++u) {
    int c = lane + u * 64;
    float t = IN_PL ? pl2f(((const uint*)in)[(size_t)row * HDIM + c])
                    : ((const float*)in)[(size_t)row * HDIM + c];
    if (bias) t += bias[c];
    v[u] = t;
    ss += t * t;
  }
#pragma unroll
  for (int off = 32; off; off >>= 1) ss += __shfl_xor(ss, off);
  float sc = 1.0f / fmaxf(sqrtf(ss), 1e-12f);
#pragma unroll
  for (int u = 0; u < 4; ++u) {
    int c = lane + u * 64;
    out_pl[(size_t)row * HDIM + c] = f2pl(v[u] * sc);
  }
}

__global__ __launch_bounds__(256) void head3_kernel(
    const float* __restrict__ h2, const float* __restrict__ W3, const float* __restrict__ b3,
    float* __restrict__ out, int M, int K) {
  int i = blockIdx.x * 4 + (threadIdx.x >> 6);
  int lane = threadIdx.x & 63;
  if (i >= M) return;
  float s0 = 0.f, s1 = 0.f;
  for (int k = lane; k < K; k += 64) {
    float h = h2[(size_t)i * K + k];
    s0 += h * W3[k * 2 + 0];
    s1 += h * W3[k * 2 + 1];
  }
#pragma unroll
  for (int off = 32; off; off >>= 1) {
    s0 += __shfl_down(s0, off);
    s1 += __shfl_down(s1, off);
  }
  if (lane == 0) {
    out[(size_t)i * 2 + 0] = s0 + b3[0];
    out[(size_t)i * 2 + 1] = s1 + b3[1];
  }
}

// ---------------------------------------------------------------- host side
static void build_sorted(hipStream_t stream,
                         const int* src, const int* dst, int E, int nloops, int Nd,
                         int* offs, int* binsum, int* rowptr, uint* sd) {
  size_t lds = (size_t)Nd * sizeof(int);
  hist_kernel<<<NB, 256, lds, stream>>>(src, dst, E, nloops, Nd, offs);
  scan_bins_kernel<<<cdiv(Nd, 4), 256, 0, stream>>>(offs, binsum, Nd);
  scan_base_kernel<<<1, 256, 0, stream>>>(binsum, rowptr, Nd);
  scatter_kernel<<<NB, 256, lds, stream>>>(src, dst, E, nloops, Nd, offs, rowptr, sd);
}

struct GatBufs {
  float *Hsrc, *Hdst, *als, *ald, *out32;
  ushort* Hb;
};

static void run_gat(hipStream_t stream,
                    const void* Xsrc, int src_mode, int Ns,
                    const void* Xdst, int dst_mode, int Nd, bool same,
                    const uint* WT, const float* asrc, const float* adst, const float* bias,
                    const uint* sd, const int* rowptr,
                    const GatBufs& b, uint* xout_pl, int act /*0=l2norm,1=relu*/) {
  launch_gemm(stream, src_mode, 2, 0, Xsrc, nullptr, nullptr, nullptr, nullptr, nullptr, 0,
              WT, nullptr, b.Hsrc, b.Hb, Ns, HDIM, HDIM);
  if (same) {
    rowdot2_kernel<<<cdiv(Ns, 4), 256, 0, stream>>>(b.Hsrc, asrc, adst, b.als, b.ald, Ns);
  } else {
    launch_gemm(stream, dst_mode, 0, 0, Xdst, nullptr, nullptr, nullptr, nullptr, nullptr, 0,
                WT, nullptr, b.Hdst, nullptr, Nd, HDIM, HDIM);
    rowdot_kernel<<<cdiv(Ns, 4), 256, 0, stream>>>(b.Hsrc, asrc, b.als, Ns);
    rowdot_kernel<<<cdiv(Nd, 4), 256, 0, stream>>>(b.Hdst, adst, b.ald, Nd);
  }
  if (Nd <= 256) {
    fillf_kernel<<<cdiv(Nd * HDIM, 256), 256, 0, stream>>>(b.out32, 0.f, Nd * HDIM);
    gat_agg_slice<<<Nd * SLICES, 256, 0, stream>>>(rowptr, sd, b.als, b.ald, b.Hb, b.out32, Nd);
    finish_relu_pl<<<cdiv(Nd * HDIM, 256), 256, 0, stream>>>(b.out32, bias, xout_pl, Nd * HDIM);
  } else if (act == 0) {
    gat_agg_small<0><<<cdiv(Nd, 4), 256, 0, stream>>>(rowptr, sd, b.als, b.ald, b.Hb, bias, xout_pl, Nd);
  } else {
    gat_agg_small<1><<<cdiv(Nd, 4), 256, 0, stream>>>(rowptr, sd, b.als, b.ald, b.Hb, bias, xout_pl, Nd);
  }
}

extern "C" void kernel_launch(void* const* d_in, const int* in_sizes, int n_in,
                              void* d_out, int out_size, void* d_ws, size_t ws_size,
                              hipStream_t stream) {
  const float* drug_emb = (const float*)d_in[0];
  const float* prot_emb = (const float*)d_in[1];
  const float* cell_emb = (const float*)d_in[2];
  const float* W_pp = (const float*)d_in[3];
  const float* as_pp = (const float*)d_in[4];
  const float* ad_pp = (const float*)d_in[5];
  const float* b_pp = (const float*)d_in[6];
  const float* W_dp = (const float*)d_in[7];
  const float* as_dp = (const float*)d_in[8];
  const float* ad_dp = (const float*)d_in[9];
  const float* b_dp = (const float*)d_in[10];
  const float* W_cp = (const float*)d_in[11];
  const float* as_cp = (const float*)d_in[12];
  const float* ad_cp = (const float*)d_in[13];
  const float* b_cp = (const float*)d_in[14];
  const float* W1 = (const float*)d_in[15];
  const float* b1 = (const float*)d_in[16];
  const float* W2 = (const float*)d_in[17];
  const float* b2 = (const float*)d_in[18];
  const float* W3 = (const float*)d_in[19];
  const float* b3 = (const float*)d_in[20];
  const int* edge_pp = (const int*)d_in[21];
  const int* edge_dp = (const int*)d_in[22];
  const int* edge_cp = (const int*)d_in[23];
  const int* drug1 = (const int*)d_in[24];
  const int* drug2 = (const int*)d_in[25];
  const int* cellb = (const int*)d_in[26];

  const int ND = in_sizes[0] / HDIM;   // 2000
  const int NP = in_sizes[1] / HDIM;   // 19000
  const int NC = in_sizes[2] / HDIM;   // 100
  const int L = in_sizes[3] / (HDIM * HDIM);  // 2
  const int E_pp = in_sizes[21] / 2;
  const int E_dp = in_sizes[22] / 2;
  const int E_cp = in_sizes[23] / 2;
  const int B = in_sizes[24];          // 8192

  const int* src_pp = edge_pp;          const int* dst_pp = edge_pp + E_pp;
  const int* src_dp = edge_dp;          const int* dst_dp = edge_dp + E_dp;
  const int* src_cp = edge_cp;          const int* dst_cp = edge_cp + E_cp;
  const int tot_pp = E_pp + NP, tot_dp = E_dp, tot_cp = E_cp;

  // ---------------- workspace (~70 MB peak)
  float* ws = (float*)d_ws;
  size_t off = 0;
  auto alloc = [&](size_t n) { float* p = ws + off; off += (n + 3) & ~(size_t)3; return p; };
  int maxN = NP > ND ? NP : ND; if (NC > maxN) maxN = NC;

  uint* xp_pl  = (uint*)alloc((size_t)NP * HDIM);
  uint* xd_pl  = (uint*)alloc((size_t)ND * HDIM);
  uint* xc_pl  = (uint*)alloc((size_t)NC * HDIM);
  uint* xdn_pl = (uint*)alloc((size_t)ND * HDIM);
  uint* xcn_pl = (uint*)alloc((size_t)NC * HDIM);
  uint* WTpp = (uint*)alloc((size_t)L * HDIM * HDIM);
  uint* WTdp = (uint*)alloc((size_t)L * HDIM * HDIM);
  uint* WTcp = (uint*)alloc((size_t)L * HDIM * HDIM);
  int* binsum = (int*)alloc(maxN);
  int* rp_pp = (int*)alloc(NP + 1);
  int* rp_dp = (int*)alloc(ND + 1);
  int* rp_cp = (int*)alloc(NC + 1);
  uint* sd_pp = (uint*)alloc(tot_pp);
  uint* sd_dp = (uint*)alloc(tot_dp);
  uint* sd_cp = (uint*)alloc(tot_cp);
  float* out32 = alloc((size_t)NC * HDIM);        // cp partial accumulator

  // scratch region S: graph bufs <-> offs (sort) <-> MLP bufs
  size_t S0 = off;
  float* Hp = ws + S0;
  float* Hd = Hp + (size_t)NP * HDIM;
  ushort* Hb = (ushort*)(Hd + (size_t)ND * HDIM);
  float* als = (float*)(Hb + (size_t)NP * HDIM);
  float* ald = als + maxN;
  // MLP overlay
  uint* W1T = (uint*)(ws + S0);                       // [1536][768]
  uint* W2T = W1T + (size_t)768 * 1536;               // [512][1536]
  const int CH = 4096;
  uint* h1_pl = W2T + (size_t)1536 * 512;             // [CH][1536] planes
  float* h2 = (float*)(h1_pl + (size_t)CH * 1536);    // [CH][512] fp32
  (void)ws_size; (void)n_in; (void)out_size;

  // ---- sort builds (offs overlays S; dead before Hp first written)
  int* offs = (int*)(ws + S0);
  build_sorted(stream, src_pp, dst_pp, E_pp, NP, NP, offs, binsum, rp_pp, sd_pp);
  build_sorted(stream, src_dp, dst_dp, E_dp, 0, ND, offs, binsum, rp_dp, sd_dp);
  build_sorted(stream, src_cp, dst_cp, E_cp, 0, NC, offs, binsum, rp_cp, sd_cp);

  // ---- weight planes (transposed)
  for (int l = 0; l < L; ++l) {
    int WOFF = l * HDIM * HDIM;
    wconv_kernel<<<cdiv(HDIM * HDIM, 256), 256, 0, stream>>>(W_pp + WOFF, WTpp + WOFF, HDIM, HDIM);
    wconv_kernel<<<cdiv(HDIM * HDIM, 256), 256, 0, stream>>>(W_dp + WOFF, WTdp + WOFF, HDIM, HDIM);
    wconv_kernel<<<cdiv(HDIM * HDIM, 256), 256, 0, stream>>>(W_cp + WOFF, WTcp + WOFF, HDIM, HDIM);
  }

  GatBufs gb{Hp, Hd, als, ald, out32, Hb};

  for (int l = 0; l < L; ++l) {
    const int WOFF = l * HDIM * HDIM, VOFF = l * HDIM;
    run_gat(stream,
            l == 0 ? (const void*)prot_emb : (const void*)xp_pl, l == 0 ? 1 : 0, NP,
            nullptr, 0, NP, /*same=*/true,
            WTpp + WOFF, as_pp + VOFF, ad_pp + VOFF, b_pp + VOFF,
            sd_pp, rp_pp, gb, xp_pl, 0);
    run_gat(stream, xp_pl, 0, NP,
            l == 0 ? (const void*)drug_emb : (const void*)xd_pl, l == 0 ? 1 : 0, ND, false,
            WTdp + WOFF, as_dp + VOFF, ad_dp + VOFF, b_dp + VOFF,
            sd_dp, rp_dp, gb, xd_pl, 1);
    run_gat(stream, xp_pl, 0, NP,
            l == 0 ? (const void*)cell_emb : (const void*)xc_pl, l == 0 ? 1 : 0, NC, false,
            WTcp + WOFF, as_cp + VOFF, ad_cp + VOFF, b_cp + VOFF,
            sd_cp, rp_cp, gb, xc_pl, 1);
  }

  // ---------------- head
  l2norm_pl_kernel<1><<<cdiv(ND, 4), 256, 0, stream>>>(xd_pl, nullptr, xdn_pl, ND);
  l2norm_pl_kernel<1><<<cdiv(NC, 4), 256, 0, stream>>>(xc_pl, nullptr, xcn_pl, NC);

  wconv_kernel<<<cdiv(768 * 1536, 256), 256, 0, stream>>>(W1, W1T, 768, 1536);
  wconv_kernel<<<cdiv(1536 * 512, 256), 256, 0, stream>>>(W2, W2T, 1536, 512);

  float* outp = (float*)d_out;
  for (int c0 = 0; c0 < B; c0 += CH) {
    int M = (B - c0) < CH ? (B - c0) : CH;
    launch_gemm(stream, 2, 1, 1, nullptr, xdn_pl, xcn_pl, drug1, drug2, cellb, c0,
                W1T, b1, h1_pl, nullptr, M, 1536, 768);
    launch_gemm(stream, 0, 0, 1, h1_pl, nullptr, nullptr, nullptr, nullptr, nullptr, 0,
                W2T, b2, h2, nullptr, M, 512, 1536);
    head3_kernel<<<cdiv(M, 4), 256, 0, stream>>>(h2, W3, b3, outp + (size_t)c0 * 2, M, 512);
  }
}